// Round 2
// baseline (2936.200 us; speedup 1.0000x reference)
//
#include <hip/hip_runtime.h>
#include <hip/hip_bf16.h>
#include <math.h>

// Problem constants
#define BB 8
#define NN 1024
#define BN 8192
#define D_IN 128
#define HH 256
#define LL 4
#define NHD 8
#define DH 32
#define EE 131072
#define EPSV 1e-5f

__device__ __forceinline__ float gelu_erf(float x) {
    return 0.5f * x * (1.0f + erff(x * 0.70710678118654752f));
}

// ---------------- CSR build ----------------
__global__ __launch_bounds__(256) void hist_kernel(const int* __restrict__ edge_row,
                                                   int* __restrict__ counts) {
    int e = blockIdx.x * 256 + threadIdx.x;
    atomicAdd(&counts[edge_row[e]], 1);
}

__global__ __launch_bounds__(256) void prefix_kernel(const int* __restrict__ counts,
                                                     int* __restrict__ row_start,
                                                     int* __restrict__ cursor) {
    __shared__ int lds[256];
    int t = threadIdx.x;
    int local[32];
    int s = 0;
#pragma unroll
    for (int i = 0; i < 32; ++i) { local[i] = counts[t * 32 + i]; s += local[i]; }
    lds[t] = s;
    __syncthreads();
    for (int off = 1; off < 256; off <<= 1) {
        int v = (t >= off) ? lds[t - off] : 0;
        __syncthreads();
        lds[t] += v;
        __syncthreads();
    }
    int excl = (t == 0) ? 0 : lds[t - 1];
#pragma unroll
    for (int i = 0; i < 32; ++i) {
        int c = local[i];
        row_start[t * 32 + i] = excl;
        cursor[t * 32 + i] = excl;
        excl += c;
    }
    if (t == 255) row_start[8192] = excl;
}

__global__ __launch_bounds__(256) void scatter_kernel(const int* __restrict__ edge_row,
                                                      int* __restrict__ cursor,
                                                      int* __restrict__ csr_e) {
    int e = blockIdx.x * 256 + threadIdx.x;
    int r = edge_row[e];
    int pos = atomicAdd(&cursor[r], 1);
    csr_e[pos] = e;
}

// ---------------- GCN gather: out[r] = gelu(sum_e val[e]*t1[col[e]]) ----------------
__global__ __launch_bounds__(256) void gcn_gather_kernel(const float* __restrict__ t1,
                                                         const int* __restrict__ row_start,
                                                         const int* __restrict__ csr_e,
                                                         const int* __restrict__ edge_col,
                                                         const float* __restrict__ edge_val,
                                                         float* __restrict__ outb) {
    int wave = threadIdx.x >> 6;
    int lane = threadIdx.x & 63;
    int r = blockIdx.x * 4 + wave;
    float4 acc = make_float4(0.f, 0.f, 0.f, 0.f);
    int p0 = row_start[r], p1 = row_start[r + 1];
    for (int p = p0; p < p1; ++p) {
        int e = csr_e[p];
        int c = edge_col[e];
        float v = edge_val[e];
        float4 src = *(const float4*)&t1[(size_t)c * HH + lane * 4];
        acc.x += v * src.x; acc.y += v * src.y; acc.z += v * src.z; acc.w += v * src.w;
    }
    float4 g;
    g.x = gelu_erf(acc.x); g.y = gelu_erf(acc.y); g.z = gelu_erf(acc.z); g.w = gelu_erf(acc.w);
    *(float4*)&outb[(size_t)r * HH + lane * 4] = g;
}

// ---------------- BatchNorm (3 phases) ----------------
// phase A: h = h + add (in place), per-chunk partial sums
__global__ __launch_bounds__(256) void bn_reduce_kernel(float* __restrict__ h,
                                                        const float* __restrict__ add,
                                                        float* __restrict__ psum,
                                                        float* __restrict__ psq) {
    int c = threadIdx.x;
    int chunk = blockIdx.x;
    int r0 = chunk * 32;
    float s = 0.f, q = 0.f;
#pragma unroll 4
    for (int i = 0; i < 32; ++i) {
        int idx = (r0 + i) * HH + c;
        float v = h[idx] + add[idx];
        h[idx] = v;
        s += v; q += v * v;
    }
    psum[chunk * HH + c] = s;
    psq[chunk * HH + c] = q;
}

__global__ __launch_bounds__(256) void bn_finalize_kernel(const float* __restrict__ psum,
                                                          const float* __restrict__ psq,
                                                          const float* __restrict__ g,
                                                          const float* __restrict__ b,
                                                          float* __restrict__ scale,
                                                          float* __restrict__ shift) {
    int c = threadIdx.x;
    float s = 0.f, q = 0.f;
    for (int i = 0; i < 256; ++i) { s += psum[i * HH + c]; q += psq[i * HH + c]; }
    float mean = s * (1.f / 8192.f);
    float var = q * (1.f / 8192.f) - mean * mean;
    float sc = g[c] * rsqrtf(var + EPSV);
    scale[c] = sc;
    shift[c] = b[c] - mean * sc;
}

__global__ __launch_bounds__(256) void bn_apply_kernel(float* __restrict__ h,
                                                       const float* __restrict__ scale,
                                                       const float* __restrict__ shift) {
    int i = blockIdx.x * 256 + threadIdx.x;   // float4 index over BN*H/4
    float4 v = ((float4*)h)[i];
    int c4 = (i & 63) * 4;                    // 64 float4 per row of 256
    v.x = v.x * scale[c4 + 0] + shift[c4 + 0];
    v.y = v.y * scale[c4 + 1] + shift[c4 + 1];
    v.z = v.z * scale[c4 + 2] + shift[c4 + 2];
    v.w = v.w * scale[c4 + 3] + shift[c4 + 3];
    ((float4*)h)[i] = v;
}

// ---------------- fp32 tiled GEMM: C[M,N] = A[M,K] @ W[N,K]^T + bias ----------------
// EPI: 0 = none, 1 = gelu(erf)
template <int EPI>
__global__ __launch_bounds__(256) void gemm_tn(const float* __restrict__ A,
                                               const float* __restrict__ W,
                                               const float* __restrict__ bias,
                                               float* __restrict__ C,
                                               int M, int K, int N) {
    __shared__ float As[16][68];
    __shared__ float Ws[16][68];
    int t = threadIdx.x;
    int bm = blockIdx.y * 64, bn = blockIdx.x * 64;
    int tx = t & 15, ty = t >> 4;
    float acc[4][4] = {};
    int lrow = t >> 2, lk = (t & 3) * 4;
    const float* Ag = A + (size_t)(bm + lrow) * K + lk;
    const float* Wg = W + (size_t)(bn + lrow) * K + lk;
    for (int k0 = 0; k0 < K; k0 += 16) {
        float4 av = *(const float4*)(Ag + k0);
        float4 wv = *(const float4*)(Wg + k0);
        __syncthreads();
        As[lk + 0][lrow] = av.x; As[lk + 1][lrow] = av.y;
        As[lk + 2][lrow] = av.z; As[lk + 3][lrow] = av.w;
        Ws[lk + 0][lrow] = wv.x; Ws[lk + 1][lrow] = wv.y;
        Ws[lk + 2][lrow] = wv.z; Ws[lk + 3][lrow] = wv.w;
        __syncthreads();
#pragma unroll
        for (int k = 0; k < 16; ++k) {
            float4 a = *(const float4*)&As[k][ty * 4];
            float4 bv = *(const float4*)&Ws[k][tx * 4];
            acc[0][0] += a.x * bv.x; acc[0][1] += a.x * bv.y; acc[0][2] += a.x * bv.z; acc[0][3] += a.x * bv.w;
            acc[1][0] += a.y * bv.x; acc[1][1] += a.y * bv.y; acc[1][2] += a.y * bv.z; acc[1][3] += a.y * bv.w;
            acc[2][0] += a.z * bv.x; acc[2][1] += a.z * bv.y; acc[2][2] += a.z * bv.z; acc[2][3] += a.z * bv.w;
            acc[3][0] += a.w * bv.x; acc[3][1] += a.w * bv.y; acc[3][2] += a.w * bv.z; acc[3][3] += a.w * bv.w;
        }
    }
    float bj[4] = {0.f, 0.f, 0.f, 0.f};
    if (bias) {
#pragma unroll
        for (int j = 0; j < 4; ++j) bj[j] = bias[bn + tx * 4 + j];
    }
#pragma unroll
    for (int i = 0; i < 4; ++i) {
        int row = bm + ty * 4 + i;
        float4 o;
        float v0 = acc[i][0] + bj[0], v1 = acc[i][1] + bj[1];
        float v2 = acc[i][2] + bj[2], v3 = acc[i][3] + bj[3];
        if (EPI == 1) { v0 = gelu_erf(v0); v1 = gelu_erf(v1); v2 = gelu_erf(v2); v3 = gelu_erf(v3); }
        o.x = v0; o.y = v1; o.z = v2; o.w = v3;
        *(float4*)(C + (size_t)row * N + bn + tx * 4) = o;
    }
}

// small K=8 GEMM accumulate: h += pe @ W_pe^T + b_pe
__global__ __launch_bounds__(256) void pe_add_kernel(const float* __restrict__ pe,
                                                     const float* __restrict__ Wpe,
                                                     const float* __restrict__ bpe,
                                                     float* __restrict__ h) {
    __shared__ float Ws[256][9];
    int t = threadIdx.x;
    for (int i = t; i < 2048; i += 256) Ws[i >> 3][i & 7] = Wpe[i];
    __syncthreads();
    int r = blockIdx.x;   // one row per block
    int c = t;
    float s = bpe[c];
    const float* pr = pe + r * 8;
#pragma unroll
    for (int k = 0; k < 8; ++k) s += pr[k] * Ws[c][k];
    h[(size_t)r * HH + c] += s;
}

// ---------------- fused attention (flash style, fp32) ----------------
// qkv: (BN, 768) rows [q(256) k(256) v(256)], per head 32 dims. o: (BN, 256)
__global__ __launch_bounds__(256) void attn_kernel(const float* __restrict__ qkv,
                                                   float* __restrict__ o) {
    __shared__ float Ks[64][36];
    __shared__ float Vs[64][36];
    int bid = blockIdx.x;
    int qt = bid & 3;
    int bh = bid >> 2;
    int head = bh & 7, b = bh >> 3;
    int qrow = qt * 256 + threadIdx.x;
    const float* qbase = qkv + (size_t)(b * NN + qrow) * 768 + head * DH;
    float q[32];
#pragma unroll
    for (int d4 = 0; d4 < 8; ++d4) {
        float4 v = *(const float4*)(qbase + d4 * 4);
        q[d4 * 4 + 0] = v.x * 0.17677669529663689f;
        q[d4 * 4 + 1] = v.y * 0.17677669529663689f;
        q[d4 * 4 + 2] = v.z * 0.17677669529663689f;
        q[d4 * 4 + 3] = v.w * 0.17677669529663689f;
    }
    float m = -1e30f, l = 0.f;
    float acc[32];
#pragma unroll
    for (int d = 0; d < 32; ++d) acc[d] = 0.f;

    for (int k0 = 0; k0 < NN; k0 += 64) {
        __syncthreads();
        for (int fid = threadIdx.x; fid < 512; fid += 256) {
            int row = fid >> 3, c4 = (fid & 7) * 4;
            const float* src = qkv + (size_t)(b * NN + k0 + row) * 768 + 256 + head * DH + c4;
            *(float4*)&Ks[row][c4] = *(const float4*)src;
            *(float4*)&Vs[row][c4] = *(const float4*)(src + 256);
        }
        __syncthreads();
        for (int kk = 0; kk < 64; ++kk) {
            float s = 0.f;
#pragma unroll
            for (int d4 = 0; d4 < 8; ++d4) {
                float4 kv = *(const float4*)&Ks[kk][d4 * 4];
                s += q[d4 * 4 + 0] * kv.x + q[d4 * 4 + 1] * kv.y +
                     q[d4 * 4 + 2] * kv.z + q[d4 * 4 + 3] * kv.w;
            }
            if (s > m) {
                float corr = __expf(m - s);
                l *= corr;
#pragma unroll
                for (int d = 0; d < 32; ++d) acc[d] *= corr;
                m = s;
            }
            float p = __expf(s - m);
            l += p;
#pragma unroll
            for (int d4 = 0; d4 < 8; ++d4) {
                float4 vv = *(const float4*)&Vs[kk][d4 * 4];
                acc[d4 * 4 + 0] += p * vv.x; acc[d4 * 4 + 1] += p * vv.y;
                acc[d4 * 4 + 2] += p * vv.z; acc[d4 * 4 + 3] += p * vv.w;
            }
        }
    }
    float inv = 1.f / l;
    float* ob = o + (size_t)(b * NN + qrow) * HH + head * DH;
#pragma unroll
    for (int d4 = 0; d4 < 8; ++d4) {
        float4 v;
        v.x = acc[d4 * 4 + 0] * inv; v.y = acc[d4 * 4 + 1] * inv;
        v.z = acc[d4 * 4 + 2] * inv; v.w = acc[d4 * 4 + 3] * inv;
        *(float4*)(ob + d4 * 4) = v;
    }
}

// ---------------- head2: out = sigmoid(g1 @ W2^T + b2), N_out=1 ----------------
__global__ __launch_bounds__(256) void head2_kernel(const float* __restrict__ g1,
                                                    const float* __restrict__ W2,
                                                    const float* __restrict__ b2,
                                                    float* __restrict__ out) {
    __shared__ float w[128];
    int t = threadIdx.x;
    if (t < 128) w[t] = W2[t];
    __syncthreads();
    int r = blockIdx.x * 256 + t;
    float s = b2[0];
    const float* row = g1 + (size_t)r * 128;
#pragma unroll
    for (int k = 0; k < 128; k += 4) {
        float4 v = *(const float4*)&row[k];
        s += v.x * w[k] + v.y * w[k + 1] + v.z * w[k + 2] + v.w * w[k + 3];
    }
    out[r] = 1.f / (1.f + __expf(-s));
}

extern "C" void kernel_launch(void* const* d_in, const int* in_sizes, int n_in,
                              void* d_out, int out_size, void* d_ws, size_t ws_size,
                              hipStream_t stream) {
    const float* x        = (const float*)d_in[0];
    const int*   edge_row = (const int*)d_in[1];
    const int*   edge_col = (const int*)d_in[2];
    const float* edge_val = (const float*)d_in[3];
    const float* pe       = (const float*)d_in[4];
    const float* W_in     = (const float*)d_in[5];
    const float* b_in     = (const float*)d_in[6];
    const float* W_pe     = (const float*)d_in[7];
    const float* b_pe     = (const float*)d_in[8];
    const float* gcn_W    = (const float*)d_in[9];
    const float* attn_in_W  = (const float*)d_in[10];
    const float* attn_in_b  = (const float*)d_in[11];
    const float* attn_out_W = (const float*)d_in[12];
    const float* attn_out_b = (const float*)d_in[13];
    const float* bn_g     = (const float*)d_in[14];
    const float* bn_b     = (const float*)d_in[15];
    const float* ffn_W1   = (const float*)d_in[16];
    const float* ffn_b1   = (const float*)d_in[17];
    const float* ffn_W2   = (const float*)d_in[18];
    const float* ffn_b2   = (const float*)d_in[19];
    const float* head_W1  = (const float*)d_in[20];
    const float* head_b1  = (const float*)d_in[21];
    const float* head_W2  = (const float*)d_in[22];
    const float* head_b2  = (const float*)d_in[23];
    float* out = (float*)d_out;

    float* w = (float*)d_ws;
    float* h    = w; w += 2097152;       // (8192,256)
    float* buf1 = w; w += 8388608;       // (8192,1024) — gcn lin / qkv / ffn mid / head mid
    float* buf2 = w; w += 2097152;       // (8192,256)
    float* buf3 = w; w += 2097152;       // (8192,256)
    float* psum = w; w += 65536;
    float* psq  = w; w += 65536;
    float* scale = w; w += 256;
    float* shift = w; w += 256;
    int* counts    = (int*)w;
    int* row_start = counts + 8192;
    int* cursor    = row_start + 8224;
    int* csr_e     = cursor + 8192;

    // CSR build (edges identical every call; rebuilt each launch for graph safety)
    hipMemsetAsync(counts, 0, 8192 * sizeof(int), stream);
    hist_kernel<<<512, 256, 0, stream>>>(edge_row, counts);
    prefix_kernel<<<1, 256, 0, stream>>>(counts, row_start, cursor);
    scatter_kernel<<<512, 256, 0, stream>>>(edge_row, cursor, csr_e);

    // input projection
    gemm_tn<0><<<dim3(4, 128), 256, 0, stream>>>(x, W_in, b_in, h, BN, D_IN, HH);
    pe_add_kernel<<<BN, 256, 0, stream>>>(pe, W_pe, b_pe, h);

    for (int l = 0; l < LL; ++l) {
        // GCN
        gemm_tn<0><<<dim3(4, 128), 256, 0, stream>>>(h, gcn_W + l * 65536, nullptr, buf1, BN, HH, HH);
        gcn_gather_kernel<<<2048, 256, 0, stream>>>(buf1, row_start, csr_e, edge_col, edge_val, buf2);
        bn_reduce_kernel<<<256, 256, 0, stream>>>(h, buf2, psum, psq);
        bn_finalize_kernel<<<1, 256, 0, stream>>>(psum, psq, bn_g + (l * 3 + 0) * 256, bn_b + (l * 3 + 0) * 256, scale, shift);
        bn_apply_kernel<<<2048, 256, 0, stream>>>(h, scale, shift);

        // attention
        gemm_tn<0><<<dim3(12, 128), 256, 0, stream>>>(h, attn_in_W + l * 768 * 256, attn_in_b + l * 768, buf1, BN, HH, 768);
        attn_kernel<<<256, 256, 0, stream>>>(buf1, buf2);
        gemm_tn<0><<<dim3(4, 128), 256, 0, stream>>>(buf2, attn_out_W + l * 65536, attn_out_b + l * 256, buf3, BN, HH, HH);
        bn_reduce_kernel<<<256, 256, 0, stream>>>(h, buf3, psum, psq);
        bn_finalize_kernel<<<1, 256, 0, stream>>>(psum, psq, bn_g + (l * 3 + 1) * 256, bn_b + (l * 3 + 1) * 256, scale, shift);
        bn_apply_kernel<<<2048, 256, 0, stream>>>(h, scale, shift);

        // FFN
        gemm_tn<1><<<dim3(16, 128), 256, 0, stream>>>(h, ffn_W1 + l * 1024 * 256, ffn_b1 + l * 1024, buf1, BN, HH, 1024);
        gemm_tn<0><<<dim3(4, 128), 256, 0, stream>>>(buf1, ffn_W2 + l * 256 * 1024, ffn_b2 + l * 256, buf2, BN, 1024, HH);
        bn_reduce_kernel<<<256, 256, 0, stream>>>(h, buf2, psum, psq);
        bn_finalize_kernel<<<1, 256, 0, stream>>>(psum, psq, bn_g + (l * 3 + 2) * 256, bn_b + (l * 3 + 2) * 256, scale, shift);
        bn_apply_kernel<<<2048, 256, 0, stream>>>(h, scale, shift);
    }

    // head
    gemm_tn<1><<<dim3(2, 128), 256, 0, stream>>>(h, head_W1, head_b1, buf1, BN, HH, 128);
    head2_kernel<<<32, 256, 0, stream>>>(buf1, head_W2, head_b2, out);
}

// Round 3
// 2417.558 us; speedup vs baseline: 1.2145x; 1.2145x over previous
//
#include <hip/hip_runtime.h>
#include <hip/hip_bf16.h>
#include <math.h>

// Problem constants
#define BB 8
#define NN 1024
#define BN 8192
#define D_IN 128
#define HH 256
#define LL 4
#define NHD 8
#define DH 32
#define EE 131072
#define EPSV 1e-5f

__device__ __forceinline__ float gelu_erf(float x) {
    return 0.5f * x * (1.0f + erff(x * 0.70710678118654752f));
}

// ---------------- CSR build ----------------
__global__ __launch_bounds__(256) void hist_kernel(const int* __restrict__ edge_row,
                                                   int* __restrict__ counts) {
    int e = blockIdx.x * 256 + threadIdx.x;
    atomicAdd(&counts[edge_row[e]], 1);
}

__global__ __launch_bounds__(256) void prefix_kernel(const int* __restrict__ counts,
                                                     int* __restrict__ row_start,
                                                     int* __restrict__ cursor) {
    __shared__ int lds[256];
    int t = threadIdx.x;
    int local[32];
    int s = 0;
#pragma unroll
    for (int i = 0; i < 32; ++i) { local[i] = counts[t * 32 + i]; s += local[i]; }
    lds[t] = s;
    __syncthreads();
    for (int off = 1; off < 256; off <<= 1) {
        int v = (t >= off) ? lds[t - off] : 0;
        __syncthreads();
        lds[t] += v;
        __syncthreads();
    }
    int excl = (t == 0) ? 0 : lds[t - 1];
#pragma unroll
    for (int i = 0; i < 32; ++i) {
        int c = local[i];
        row_start[t * 32 + i] = excl;
        cursor[t * 32 + i] = excl;
        excl += c;
    }
    if (t == 255) row_start[8192] = excl;
}

__global__ __launch_bounds__(256) void scatter_kernel(const int* __restrict__ edge_row,
                                                      int* __restrict__ cursor,
                                                      int* __restrict__ csr_e) {
    int e = blockIdx.x * 256 + threadIdx.x;
    int r = edge_row[e];
    int pos = atomicAdd(&cursor[r], 1);
    csr_e[pos] = e;
}

// ---------------- GCN gather: out[r] = gelu(sum_e val[e]*t1[col[e]]) ----------------
__global__ __launch_bounds__(256) void gcn_gather_kernel(const float* __restrict__ t1,
                                                         const int* __restrict__ row_start,
                                                         const int* __restrict__ csr_e,
                                                         const int* __restrict__ edge_col,
                                                         const float* __restrict__ edge_val,
                                                         float* __restrict__ outb) {
    int wave = threadIdx.x >> 6;
    int lane = threadIdx.x & 63;
    int r = blockIdx.x * 4 + wave;
    float4 acc = make_float4(0.f, 0.f, 0.f, 0.f);
    int p0 = row_start[r], p1 = row_start[r + 1];
    for (int p = p0; p < p1; ++p) {
        int e = csr_e[p];
        int c = edge_col[e];
        float v = edge_val[e];
        float4 src = *(const float4*)&t1[(size_t)c * HH + lane * 4];
        acc.x += v * src.x; acc.y += v * src.y; acc.z += v * src.z; acc.w += v * src.w;
    }
    float4 g;
    g.x = gelu_erf(acc.x); g.y = gelu_erf(acc.y); g.z = gelu_erf(acc.z); g.w = gelu_erf(acc.w);
    *(float4*)&outb[(size_t)r * HH + lane * 4] = g;
}

// ---------------- BatchNorm (3 phases) ----------------
__global__ __launch_bounds__(256) void bn_reduce_kernel(float* __restrict__ h,
                                                        const float* __restrict__ add,
                                                        float* __restrict__ psum,
                                                        float* __restrict__ psq) {
    int c = threadIdx.x;
    int chunk = blockIdx.x;
    int r0 = chunk * 32;
    float s = 0.f, q = 0.f;
#pragma unroll 4
    for (int i = 0; i < 32; ++i) {
        int idx = (r0 + i) * HH + c;
        float v = h[idx] + add[idx];
        h[idx] = v;
        s += v; q += v * v;
    }
    psum[chunk * HH + c] = s;
    psq[chunk * HH + c] = q;
}

__global__ __launch_bounds__(256) void bn_finalize_kernel(const float* __restrict__ psum,
                                                          const float* __restrict__ psq,
                                                          const float* __restrict__ g,
                                                          const float* __restrict__ b,
                                                          float* __restrict__ scale,
                                                          float* __restrict__ shift) {
    int c = threadIdx.x;
    float s = 0.f, q = 0.f;
    for (int i = 0; i < 256; ++i) { s += psum[i * HH + c]; q += psq[i * HH + c]; }
    float mean = s * (1.f / 8192.f);
    float var = q * (1.f / 8192.f) - mean * mean;
    float sc = g[c] * rsqrtf(var + EPSV);
    scale[c] = sc;
    shift[c] = b[c] - mean * sc;
}

__global__ __launch_bounds__(256) void bn_apply_kernel(float* __restrict__ h,
                                                       const float* __restrict__ scale,
                                                       const float* __restrict__ shift) {
    int i = blockIdx.x * 256 + threadIdx.x;   // float4 index over BN*H/4
    float4 v = ((float4*)h)[i];
    int c4 = (i & 63) * 4;                    // 64 float4 per row of 256
    v.x = v.x * scale[c4 + 0] + shift[c4 + 0];
    v.y = v.y * scale[c4 + 1] + shift[c4 + 1];
    v.z = v.z * scale[c4 + 2] + shift[c4 + 2];
    v.w = v.w * scale[c4 + 3] + shift[c4 + 3];
    ((float4*)h)[i] = v;
}

// ---------------- fp32 tiled GEMM: C[M,N] = A[M,K] @ W[N,K]^T + bias ----------------
// EPI: 0 = none, 1 = gelu(erf)
template <int EPI>
__global__ __launch_bounds__(256) void gemm_tn(const float* __restrict__ A,
                                               const float* __restrict__ W,
                                               const float* __restrict__ bias,
                                               float* __restrict__ C,
                                               int M, int K, int N) {
    __shared__ float As[16][68];
    __shared__ float Ws[16][68];
    int t = threadIdx.x;
    int bm = blockIdx.y * 64, bn = blockIdx.x * 64;
    int tx = t & 15, ty = t >> 4;
    float acc[4][4] = {};
    int lrow = t >> 2, lk = (t & 3) * 4;
    const float* Ag = A + (size_t)(bm + lrow) * K + lk;
    const float* Wg = W + (size_t)(bn + lrow) * K + lk;
    for (int k0 = 0; k0 < K; k0 += 16) {
        float4 av = *(const float4*)(Ag + k0);
        float4 wv = *(const float4*)(Wg + k0);
        __syncthreads();
        As[lk + 0][lrow] = av.x; As[lk + 1][lrow] = av.y;
        As[lk + 2][lrow] = av.z; As[lk + 3][lrow] = av.w;
        Ws[lk + 0][lrow] = wv.x; Ws[lk + 1][lrow] = wv.y;
        Ws[lk + 2][lrow] = wv.z; Ws[lk + 3][lrow] = wv.w;
        __syncthreads();
#pragma unroll
        for (int k = 0; k < 16; ++k) {
            float4 a = *(const float4*)&As[k][ty * 4];
            float4 bv = *(const float4*)&Ws[k][tx * 4];
            acc[0][0] += a.x * bv.x; acc[0][1] += a.x * bv.y; acc[0][2] += a.x * bv.z; acc[0][3] += a.x * bv.w;
            acc[1][0] += a.y * bv.x; acc[1][1] += a.y * bv.y; acc[1][2] += a.y * bv.z; acc[1][3] += a.y * bv.w;
            acc[2][0] += a.z * bv.x; acc[2][1] += a.z * bv.y; acc[2][2] += a.z * bv.z; acc[2][3] += a.z * bv.w;
            acc[3][0] += a.w * bv.x; acc[3][1] += a.w * bv.y; acc[3][2] += a.w * bv.z; acc[3][3] += a.w * bv.w;
        }
    }
    float bj[4] = {0.f, 0.f, 0.f, 0.f};
    if (bias) {
#pragma unroll
        for (int j = 0; j < 4; ++j) bj[j] = bias[bn + tx * 4 + j];
    }
#pragma unroll
    for (int i = 0; i < 4; ++i) {
        int row = bm + ty * 4 + i;
        float4 o;
        float v0 = acc[i][0] + bj[0], v1 = acc[i][1] + bj[1];
        float v2 = acc[i][2] + bj[2], v3 = acc[i][3] + bj[3];
        if (EPI == 1) { v0 = gelu_erf(v0); v1 = gelu_erf(v1); v2 = gelu_erf(v2); v3 = gelu_erf(v3); }
        o.x = v0; o.y = v1; o.z = v2; o.w = v3;
        *(float4*)(C + (size_t)row * N + bn + tx * 4) = o;
    }
}

// small K=8 GEMM accumulate: h += pe @ W_pe^T + b_pe
__global__ __launch_bounds__(256) void pe_add_kernel(const float* __restrict__ pe,
                                                     const float* __restrict__ Wpe,
                                                     const float* __restrict__ bpe,
                                                     float* __restrict__ h) {
    __shared__ float Ws[256][9];
    int t = threadIdx.x;
    for (int i = t; i < 2048; i += 256) Ws[i >> 3][i & 7] = Wpe[i];
    __syncthreads();
    int r = blockIdx.x;   // one row per block
    int c = t;
    float s = bpe[c];
    const float* pr = pe + r * 8;
#pragma unroll
    for (int k = 0; k < 8; ++k) s += pr[k] * Ws[c][k];
    h[(size_t)r * HH + c] += s;
}

// ---------------- fused attention (flash style, fp32, 4 threads per query row) ----------------
// qkv: (BN, 768) rows [q(256) k(256) v(256)], per head 32 dims. o: (BN, 256)
// grid: 8b * 8h * 16 qtiles = 1024 blocks of 256 threads.
// Each block: 64 query rows; 4 threads per row split the key range (strided by 4
// within each 64-row K/V tile), private online-softmax state, merged at the end
// with a 2-round __shfl_xor butterfly (lane quads never straddle a wave).
__global__ __launch_bounds__(256) void attn_kernel(const float* __restrict__ qkv,
                                                   float* __restrict__ o) {
    __shared__ float Ks[64][36];
    __shared__ float Vs[64][36];
    int bid = blockIdx.x;
    int qt = bid & 15;
    int bh = bid >> 4;
    int head = bh & 7, b = bh >> 3;
    int t = threadIdx.x;
    int qlocal = t >> 2;      // 0..63
    int part = t & 3;         // 0..3
    int qrow = qt * 64 + qlocal;
    const float* qbase = qkv + (size_t)(b * NN + qrow) * 768 + head * DH;
    float q[32];
#pragma unroll
    for (int d4 = 0; d4 < 8; ++d4) {
        float4 v = *(const float4*)(qbase + d4 * 4);
        q[d4 * 4 + 0] = v.x * 0.17677669529663689f;
        q[d4 * 4 + 1] = v.y * 0.17677669529663689f;
        q[d4 * 4 + 2] = v.z * 0.17677669529663689f;
        q[d4 * 4 + 3] = v.w * 0.17677669529663689f;
    }
    float m = -1e30f, l = 0.f;
    float acc[32];
#pragma unroll
    for (int d = 0; d < 32; ++d) acc[d] = 0.f;

    for (int k0 = 0; k0 < NN; k0 += 64) {
        __syncthreads();
        for (int fid = t; fid < 512; fid += 256) {
            int row = fid >> 3, c4 = (fid & 7) * 4;
            const float* src = qkv + (size_t)(b * NN + k0 + row) * 768 + 256 + head * DH + c4;
            *(float4*)&Ks[row][c4] = *(const float4*)src;
            *(float4*)&Vs[row][c4] = *(const float4*)(src + 256);
        }
        __syncthreads();
#pragma unroll 4
        for (int kk2 = 0; kk2 < 16; ++kk2) {
            int kk = kk2 * 4 + part;
            float s = 0.f;
#pragma unroll
            for (int d4 = 0; d4 < 8; ++d4) {
                float4 kv = *(const float4*)&Ks[kk][d4 * 4];
                s += q[d4 * 4 + 0] * kv.x + q[d4 * 4 + 1] * kv.y +
                     q[d4 * 4 + 2] * kv.z + q[d4 * 4 + 3] * kv.w;
            }
            if (s > m) {
                float corr = __expf(m - s);
                l *= corr;
#pragma unroll
                for (int d = 0; d < 32; ++d) acc[d] *= corr;
                m = s;
            }
            float p = __expf(s - m);
            l += p;
#pragma unroll
            for (int d4 = 0; d4 < 8; ++d4) {
                float4 vv = *(const float4*)&Vs[kk][d4 * 4];
                acc[d4 * 4 + 0] += p * vv.x; acc[d4 * 4 + 1] += p * vv.y;
                acc[d4 * 4 + 2] += p * vv.z; acc[d4 * 4 + 3] += p * vv.w;
            }
        }
    }

    // butterfly merge of the 4 partial online-softmax states (lanes t^1, t^2)
#pragma unroll
    for (int off = 1; off < 4; off <<= 1) {
        float m2 = __shfl_xor(m, off);
        float l2 = __shfl_xor(l, off);
        float mn = fmaxf(m, m2);
        float ca = __expf(m - mn);
        float cb = __expf(m2 - mn);
        l = l * ca + l2 * cb;
#pragma unroll
        for (int d = 0; d < 32; ++d) {
            float a2 = __shfl_xor(acc[d], off);
            acc[d] = acc[d] * ca + a2 * cb;
        }
        m = mn;
    }

    if (part == 0) {
        float inv = 1.f / l;
        float* ob = o + (size_t)(b * NN + qrow) * HH + head * DH;
#pragma unroll
        for (int d4 = 0; d4 < 8; ++d4) {
            float4 v;
            v.x = acc[d4 * 4 + 0] * inv; v.y = acc[d4 * 4 + 1] * inv;
            v.z = acc[d4 * 4 + 2] * inv; v.w = acc[d4 * 4 + 3] * inv;
            *(float4*)(ob + d4 * 4) = v;
        }
    }
}

// ---------------- head2: out = sigmoid(g1 @ W2^T + b2), N_out=1 ----------------
__global__ __launch_bounds__(256) void head2_kernel(const float* __restrict__ g1,
                                                    const float* __restrict__ W2,
                                                    const float* __restrict__ b2,
                                                    float* __restrict__ out) {
    __shared__ float w[128];
    int t = threadIdx.x;
    if (t < 128) w[t] = W2[t];
    __syncthreads();
    int r = blockIdx.x * 256 + t;
    float s = b2[0];
    const float* row = g1 + (size_t)r * 128;
#pragma unroll
    for (int k = 0; k < 128; k += 4) {
        float4 v = *(const float4*)&row[k];
        s += v.x * w[k] + v.y * w[k + 1] + v.z * w[k + 2] + v.w * w[k + 3];
    }
    out[r] = 1.f / (1.f + __expf(-s));
}

extern "C" void kernel_launch(void* const* d_in, const int* in_sizes, int n_in,
                              void* d_out, int out_size, void* d_ws, size_t ws_size,
                              hipStream_t stream) {
    const float* x        = (const float*)d_in[0];
    const int*   edge_row = (const int*)d_in[1];
    const int*   edge_col = (const int*)d_in[2];
    const float* edge_val = (const float*)d_in[3];
    const float* pe       = (const float*)d_in[4];
    const float* W_in     = (const float*)d_in[5];
    const float* b_in     = (const float*)d_in[6];
    const float* W_pe     = (const float*)d_in[7];
    const float* b_pe     = (const float*)d_in[8];
    const float* gcn_W    = (const float*)d_in[9];
    const float* attn_in_W  = (const float*)d_in[10];
    const float* attn_in_b  = (const float*)d_in[11];
    const float* attn_out_W = (const float*)d_in[12];
    const float* attn_out_b = (const float*)d_in[13];
    const float* bn_g     = (const float*)d_in[14];
    const float* bn_b     = (const float*)d_in[15];
    const float* ffn_W1   = (const float*)d_in[16];
    const float* ffn_b1   = (const float*)d_in[17];
    const float* ffn_W2   = (const float*)d_in[18];
    const float* ffn_b2   = (const float*)d_in[19];
    const float* head_W1  = (const float*)d_in[20];
    const float* head_b1  = (const float*)d_in[21];
    const float* head_W2  = (const float*)d_in[22];
    const float* head_b2  = (const float*)d_in[23];
    float* out = (float*)d_out;

    float* w = (float*)d_ws;
    float* h    = w; w += 2097152;       // (8192,256)
    float* buf1 = w; w += 8388608;       // (8192,1024) — gcn lin / qkv / ffn mid / head mid
    float* buf2 = w; w += 2097152;       // (8192,256)
    float* buf3 = w; w += 2097152;       // (8192,256)
    float* psum = w; w += 65536;
    float* psq  = w; w += 65536;
    float* scale = w; w += 256;
    float* shift = w; w += 256;
    int* counts    = (int*)w;
    int* row_start = counts + 8192;
    int* cursor    = row_start + 8224;
    int* csr_e     = cursor + 8192;

    // CSR build (edges identical every call; rebuilt each launch for graph safety)
    hipMemsetAsync(counts, 0, 8192 * sizeof(int), stream);
    hist_kernel<<<512, 256, 0, stream>>>(edge_row, counts);
    prefix_kernel<<<1, 256, 0, stream>>>(counts, row_start, cursor);
    scatter_kernel<<<512, 256, 0, stream>>>(edge_row, cursor, csr_e);

    // input projection
    gemm_tn<0><<<dim3(4, 128), 256, 0, stream>>>(x, W_in, b_in, h, BN, D_IN, HH);
    pe_add_kernel<<<BN, 256, 0, stream>>>(pe, W_pe, b_pe, h);

    for (int l = 0; l < LL; ++l) {
        // GCN
        gemm_tn<0><<<dim3(4, 128), 256, 0, stream>>>(h, gcn_W + l * 65536, nullptr, buf1, BN, HH, HH);
        gcn_gather_kernel<<<2048, 256, 0, stream>>>(buf1, row_start, csr_e, edge_col, edge_val, buf2);
        bn_reduce_kernel<<<256, 256, 0, stream>>>(h, buf2, psum, psq);
        bn_finalize_kernel<<<1, 256, 0, stream>>>(psum, psq, bn_g + (l * 3 + 0) * 256, bn_b + (l * 3 + 0) * 256, scale, shift);
        bn_apply_kernel<<<2048, 256, 0, stream>>>(h, scale, shift);

        // attention
        gemm_tn<0><<<dim3(12, 128), 256, 0, stream>>>(h, attn_in_W + l * 768 * 256, attn_in_b + l * 768, buf1, BN, HH, 768);
        attn_kernel<<<1024, 256, 0, stream>>>(buf1, buf2);
        gemm_tn<0><<<dim3(4, 128), 256, 0, stream>>>(buf2, attn_out_W + l * 65536, attn_out_b + l * 256, buf3, BN, HH, HH);
        bn_reduce_kernel<<<256, 256, 0, stream>>>(h, buf3, psum, psq);
        bn_finalize_kernel<<<1, 256, 0, stream>>>(psum, psq, bn_g + (l * 3 + 1) * 256, bn_b + (l * 3 + 1) * 256, scale, shift);
        bn_apply_kernel<<<2048, 256, 0, stream>>>(h, scale, shift);

        // FFN
        gemm_tn<1><<<dim3(16, 128), 256, 0, stream>>>(h, ffn_W1 + l * 1024 * 256, ffn_b1 + l * 1024, buf1, BN, HH, 1024);
        gemm_tn<0><<<dim3(4, 128), 256, 0, stream>>>(buf1, ffn_W2 + l * 256 * 1024, ffn_b2 + l * 256, buf2, BN, 1024, HH);
        bn_reduce_kernel<<<256, 256, 0, stream>>>(h, buf2, psum, psq);
        bn_finalize_kernel<<<1, 256, 0, stream>>>(psum, psq, bn_g + (l * 3 + 2) * 256, bn_b + (l * 3 + 2) * 256, scale, shift);
        bn_apply_kernel<<<2048, 256, 0, stream>>>(h, scale, shift);
    }

    // head
    gemm_tn<1><<<dim3(2, 128), 256, 0, stream>>>(h, head_W1, head_b1, buf1, BN, HH, 128);
    head2_kernel<<<32, 256, 0, stream>>>(buf1, head_W2, head_b2, out);
}

// Round 4
// 1573.215 us; speedup vs baseline: 1.8664x; 1.5367x over previous
//
#include <hip/hip_runtime.h>
#include <hip/hip_bf16.h>
#include <math.h>

// Problem constants
#define BB 8
#define NN 1024
#define BN 8192
#define D_IN 128
#define HH 256
#define LL 4
#define NHD 8
#define DH 32
#define EE 131072
#define EPSV 1e-5f

typedef unsigned short u16;
typedef __attribute__((ext_vector_type(8))) short bf16x8;
typedef __attribute__((ext_vector_type(4))) float f32x4;

__device__ __forceinline__ float gelu_erf(float x) {
    return 0.5f * x * (1.0f + erff(x * 0.70710678118654752f));
}

__device__ __forceinline__ u16 f2bf(float v) {
    __hip_bfloat16 b = __float2bfloat16(v);   // RNE
    return *reinterpret_cast<u16*>(&b);
}

// ---------------- fp32 -> bf16 cast (4 elems/thread) ----------------
__global__ __launch_bounds__(256) void cast_bf16_kernel(const float* __restrict__ in,
                                                        u16* __restrict__ out) {
    int i = blockIdx.x * 256 + threadIdx.x;
    float4 v = ((const float4*)in)[i];
    ushort4 o;
    o.x = f2bf(v.x); o.y = f2bf(v.y); o.z = f2bf(v.z); o.w = f2bf(v.w);
    ((ushort4*)out)[i] = o;
}

// ---------------- CSR build ----------------
__global__ __launch_bounds__(256) void hist_kernel(const int* __restrict__ edge_row,
                                                   int* __restrict__ counts) {
    int e = blockIdx.x * 256 + threadIdx.x;
    atomicAdd(&counts[edge_row[e]], 1);
}

__global__ __launch_bounds__(256) void prefix_kernel(const int* __restrict__ counts,
                                                     int* __restrict__ row_start,
                                                     int* __restrict__ cursor) {
    __shared__ int lds[256];
    int t = threadIdx.x;
    int local[32];
    int s = 0;
#pragma unroll
    for (int i = 0; i < 32; ++i) { local[i] = counts[t * 32 + i]; s += local[i]; }
    lds[t] = s;
    __syncthreads();
    for (int off = 1; off < 256; off <<= 1) {
        int v = (t >= off) ? lds[t - off] : 0;
        __syncthreads();
        lds[t] += v;
        __syncthreads();
    }
    int excl = (t == 0) ? 0 : lds[t - 1];
#pragma unroll
    for (int i = 0; i < 32; ++i) {
        int c = local[i];
        row_start[t * 32 + i] = excl;
        cursor[t * 32 + i] = excl;
        excl += c;
    }
    if (t == 255) row_start[8192] = excl;
}

__global__ __launch_bounds__(256) void scatter_kernel(const int* __restrict__ edge_row,
                                                      int* __restrict__ cursor,
                                                      int* __restrict__ csr_e) {
    int e = blockIdx.x * 256 + threadIdx.x;
    int r = edge_row[e];
    int pos = atomicAdd(&cursor[r], 1);
    csr_e[pos] = e;
}

// ---------------- GCN gather: out[r] = gelu(sum_e val[e]*t1[col[e]]) ----------------
__global__ __launch_bounds__(256) void gcn_gather_kernel(const float* __restrict__ t1,
                                                         const int* __restrict__ row_start,
                                                         const int* __restrict__ csr_e,
                                                         const int* __restrict__ edge_col,
                                                         const float* __restrict__ edge_val,
                                                         float* __restrict__ outb) {
    int wave = threadIdx.x >> 6;
    int lane = threadIdx.x & 63;
    int r = blockIdx.x * 4 + wave;
    float4 acc = make_float4(0.f, 0.f, 0.f, 0.f);
    int p0 = row_start[r], p1 = row_start[r + 1];
    for (int p = p0; p < p1; ++p) {
        int e = csr_e[p];
        int c = edge_col[e];
        float v = edge_val[e];
        float4 src = *(const float4*)&t1[(size_t)c * HH + lane * 4];
        acc.x += v * src.x; acc.y += v * src.y; acc.z += v * src.z; acc.w += v * src.w;
    }
    float4 g;
    g.x = gelu_erf(acc.x); g.y = gelu_erf(acc.y); g.z = gelu_erf(acc.z); g.w = gelu_erf(acc.w);
    *(float4*)&outb[(size_t)r * HH + lane * 4] = g;
}

// ---------------- BatchNorm (3 phases) ----------------
__global__ __launch_bounds__(256) void bn_reduce_kernel(float* __restrict__ h,
                                                        const float* __restrict__ add,
                                                        float* __restrict__ psum,
                                                        float* __restrict__ psq) {
    int c = threadIdx.x;
    int chunk = blockIdx.x;
    int r0 = chunk * 32;
    float s = 0.f, q = 0.f;
#pragma unroll 4
    for (int i = 0; i < 32; ++i) {
        int idx = (r0 + i) * HH + c;
        float v = h[idx] + add[idx];
        h[idx] = v;
        s += v; q += v * v;
    }
    psum[chunk * HH + c] = s;
    psq[chunk * HH + c] = q;
}

__global__ __launch_bounds__(256) void bn_finalize_kernel(const float* __restrict__ psum,
                                                          const float* __restrict__ psq,
                                                          const float* __restrict__ g,
                                                          const float* __restrict__ b,
                                                          float* __restrict__ scale,
                                                          float* __restrict__ shift) {
    int c = threadIdx.x;
    float s = 0.f, q = 0.f;
    for (int i = 0; i < 256; ++i) { s += psum[i * HH + c]; q += psq[i * HH + c]; }
    float mean = s * (1.f / 8192.f);
    float var = q * (1.f / 8192.f) - mean * mean;
    float sc = g[c] * rsqrtf(var + EPSV);
    scale[c] = sc;
    shift[c] = b[c] - mean * sc;
}

// writes fp32 h and bf16 hb
__global__ __launch_bounds__(256) void bn_apply_kernel(float* __restrict__ h,
                                                       u16* __restrict__ hb,
                                                       const float* __restrict__ scale,
                                                       const float* __restrict__ shift) {
    int i = blockIdx.x * 256 + threadIdx.x;   // float4 index over BN*H/4
    float4 v = ((float4*)h)[i];
    int c4 = (i & 63) * 4;                    // 64 float4 per row of 256
    v.x = v.x * scale[c4 + 0] + shift[c4 + 0];
    v.y = v.y * scale[c4 + 1] + shift[c4 + 1];
    v.z = v.z * scale[c4 + 2] + shift[c4 + 2];
    v.w = v.w * scale[c4 + 3] + shift[c4 + 3];
    ((float4*)h)[i] = v;
    ushort4 o;
    o.x = f2bf(v.x); o.y = f2bf(v.y); o.z = f2bf(v.z); o.w = f2bf(v.w);
    ((ushort4*)hb)[i] = o;
}

// ---------------- bf16 MFMA GEMM: C[M,N] = A[M,K] @ W[N,K]^T + bias ----------------
// A, W bf16 (row-major, K contiguous). BM=128, BN=64, BK=64.
// 256 threads = 4 waves in 2x2 grid; each wave owns 64x32 via acc[4][2] 16x16 frags.
// LDS XOR-swizzle: col8 ^= (row&7)<<3 -> staging writes and ds_read_b128 are <=2-way.
// EPI: 0=none 1=gelu ; OUTBF: 0=fp32 C, 1=bf16 C.
#define SWZ(row, c8) ((c8) ^ (((row) & 7) << 3))
template <int EPI, int OUTBF>
__global__ __launch_bounds__(256) void gemm_mfma(const u16* __restrict__ A,
                                                 const u16* __restrict__ W,
                                                 const float* __restrict__ bias,
                                                 void* __restrict__ Cout,
                                                 int M, int K, int N) {
    __shared__ u16 As[128][64];
    __shared__ u16 Ws[64][64];
    int t = threadIdx.x;
    int bm = blockIdx.y * 128, bn = blockIdx.x * 64;
    int wid = t >> 6, lane = t & 63;
    int wr = wid >> 1, wc = wid & 1;
    int lr = lane & 15, lg = lane >> 4;

    f32x4 zero = {0.f, 0.f, 0.f, 0.f};
    f32x4 acc[4][2];
#pragma unroll
    for (int mi = 0; mi < 4; ++mi)
#pragma unroll
        for (int ni = 0; ni < 2; ++ni) acc[mi][ni] = zero;

    int sr = t >> 3;            // 0..31 staging row
    int c8 = (t & 7) * 8;       // 0..56 staging col (8 bf16 = 16B)

    for (int k0 = 0; k0 < K; k0 += 64) {
        __syncthreads();
#pragma unroll
        for (int p = 0; p < 4; ++p) {
            int row = sr + p * 32;
            const u16* src = A + (size_t)(bm + row) * K + k0 + c8;
            *(int4*)&As[row][SWZ(row, c8)] = *(const int4*)src;
        }
#pragma unroll
        for (int p = 0; p < 2; ++p) {
            int row = sr + p * 32;
            const u16* src = W + (size_t)(bn + row) * K + k0 + c8;
            *(int4*)&Ws[row][SWZ(row, c8)] = *(const int4*)src;
        }
        __syncthreads();
#pragma unroll
        for (int kk = 0; kk < 2; ++kk) {
            bf16x8 af[4], bf[2];
#pragma unroll
            for (int mi = 0; mi < 4; ++mi) {
                int row = wr * 64 + mi * 16 + lr;
                af[mi] = *(const bf16x8*)&As[row][SWZ(row, kk * 32 + lg * 8)];
            }
#pragma unroll
            for (int ni = 0; ni < 2; ++ni) {
                int row = wc * 32 + ni * 16 + lr;
                bf[ni] = *(const bf16x8*)&Ws[row][SWZ(row, kk * 32 + lg * 8)];
            }
#pragma unroll
            for (int mi = 0; mi < 4; ++mi)
#pragma unroll
                for (int ni = 0; ni < 2; ++ni)
                    acc[mi][ni] = __builtin_amdgcn_mfma_f32_16x16x32_bf16(af[mi], bf[ni], acc[mi][ni], 0, 0, 0);
        }
    }

    // epilogue: D[row=(lane>>4)*4+r][col=lane&15] per 16x16 frag (m89-verified)
#pragma unroll
    for (int ni = 0; ni < 2; ++ni) {
        int col = bn + wc * 32 + ni * 16 + lr;
        float bj = bias ? bias[col] : 0.f;
#pragma unroll
        for (int mi = 0; mi < 4; ++mi) {
#pragma unroll
            for (int r = 0; r < 4; ++r) {
                int row = bm + wr * 64 + mi * 16 + lg * 4 + r;
                float v = acc[mi][ni][r] + bj;
                if (EPI == 1) v = gelu_erf(v);
                if (OUTBF)
                    ((u16*)Cout)[(size_t)row * N + col] = f2bf(v);
                else
                    ((float*)Cout)[(size_t)row * N + col] = v;
            }
        }
    }
}

// small K=8 GEMM accumulate: h += pe @ W_pe^T + b_pe ; also emits bf16 hb
__global__ __launch_bounds__(256) void pe_add_kernel(const float* __restrict__ pe,
                                                     const float* __restrict__ Wpe,
                                                     const float* __restrict__ bpe,
                                                     float* __restrict__ h,
                                                     u16* __restrict__ hb) {
    __shared__ float Ws[256][9];
    int t = threadIdx.x;
    for (int i = t; i < 2048; i += 256) Ws[i >> 3][i & 7] = Wpe[i];
    __syncthreads();
    int r = blockIdx.x;   // one row per block
    int c = t;
    float s = bpe[c];
    const float* pr = pe + r * 8;
#pragma unroll
    for (int k = 0; k < 8; ++k) s += pr[k] * Ws[c][k];
    float nv = h[(size_t)r * HH + c] + s;
    h[(size_t)r * HH + c] = nv;
    hb[(size_t)r * HH + c] = f2bf(nv);
}

// ---------------- fused attention (flash style, fp32, 4 threads per query row) ----------------
// qkv: (BN, 768) fp32 rows [q k v]; o: (BN, 256) bf16 (feeds out-proj MFMA GEMM)
__global__ __launch_bounds__(256) void attn_kernel(const float* __restrict__ qkv,
                                                   u16* __restrict__ o) {
    __shared__ float Ks[64][36];
    __shared__ float Vs[64][36];
    int bid = blockIdx.x;
    int qt = bid & 15;
    int bh = bid >> 4;
    int head = bh & 7, b = bh >> 3;
    int t = threadIdx.x;
    int qlocal = t >> 2;      // 0..63
    int part = t & 3;         // 0..3
    int qrow = qt * 64 + qlocal;
    const float* qbase = qkv + (size_t)(b * NN + qrow) * 768 + head * DH;
    float q[32];
#pragma unroll
    for (int d4 = 0; d4 < 8; ++d4) {
        float4 v = *(const float4*)(qbase + d4 * 4);
        q[d4 * 4 + 0] = v.x * 0.17677669529663689f;
        q[d4 * 4 + 1] = v.y * 0.17677669529663689f;
        q[d4 * 4 + 2] = v.z * 0.17677669529663689f;
        q[d4 * 4 + 3] = v.w * 0.17677669529663689f;
    }
    float m = -1e30f, l = 0.f;
    float acc[32];
#pragma unroll
    for (int d = 0; d < 32; ++d) acc[d] = 0.f;

    for (int k0 = 0; k0 < NN; k0 += 64) {
        __syncthreads();
        for (int fid = t; fid < 512; fid += 256) {
            int row = fid >> 3, c4 = (fid & 7) * 4;
            const float* src = qkv + (size_t)(b * NN + k0 + row) * 768 + 256 + head * DH + c4;
            *(float4*)&Ks[row][c4] = *(const float4*)src;
            *(float4*)&Vs[row][c4] = *(const float4*)(src + 256);
        }
        __syncthreads();
#pragma unroll 4
        for (int kk2 = 0; kk2 < 16; ++kk2) {
            int kk = kk2 * 4 + part;
            float s = 0.f;
#pragma unroll
            for (int d4 = 0; d4 < 8; ++d4) {
                float4 kv = *(const float4*)&Ks[kk][d4 * 4];
                s += q[d4 * 4 + 0] * kv.x + q[d4 * 4 + 1] * kv.y +
                     q[d4 * 4 + 2] * kv.z + q[d4 * 4 + 3] * kv.w;
            }
            if (s > m) {
                float corr = __expf(m - s);
                l *= corr;
#pragma unroll
                for (int d = 0; d < 32; ++d) acc[d] *= corr;
                m = s;
            }
            float p = __expf(s - m);
            l += p;
#pragma unroll
            for (int d4 = 0; d4 < 8; ++d4) {
                float4 vv = *(const float4*)&Vs[kk][d4 * 4];
                acc[d4 * 4 + 0] += p * vv.x; acc[d4 * 4 + 1] += p * vv.y;
                acc[d4 * 4 + 2] += p * vv.z; acc[d4 * 4 + 3] += p * vv.w;
            }
        }
    }

    // butterfly merge of the 4 partial online-softmax states
#pragma unroll
    for (int off = 1; off < 4; off <<= 1) {
        float m2 = __shfl_xor(m, off);
        float l2 = __shfl_xor(l, off);
        float mn = fmaxf(m, m2);
        float ca = __expf(m - mn);
        float cb = __expf(m2 - mn);
        l = l * ca + l2 * cb;
#pragma unroll
        for (int d = 0; d < 32; ++d) {
            float a2 = __shfl_xor(acc[d], off);
            acc[d] = acc[d] * ca + a2 * cb;
        }
        m = mn;
    }

    if (part == 0) {
        float inv = 1.f / l;
        u16* ob = o + (size_t)(b * NN + qrow) * HH + head * DH;
#pragma unroll
        for (int d4 = 0; d4 < 8; ++d4) {
            ushort4 w4;
            w4.x = f2bf(acc[d4 * 4 + 0] * inv);
            w4.y = f2bf(acc[d4 * 4 + 1] * inv);
            w4.z = f2bf(acc[d4 * 4 + 2] * inv);
            w4.w = f2bf(acc[d4 * 4 + 3] * inv);
            *(ushort4*)(ob + d4 * 4) = w4;
        }
    }
}

// ---------------- head2: out = sigmoid(g1 @ W2^T + b2), N_out=1 ----------------
__global__ __launch_bounds__(256) void head2_kernel(const float* __restrict__ g1,
                                                    const float* __restrict__ W2,
                                                    const float* __restrict__ b2,
                                                    float* __restrict__ out) {
    __shared__ float w[128];
    int t = threadIdx.x;
    if (t < 128) w[t] = W2[t];
    __syncthreads();
    int r = blockIdx.x * 256 + t;
    float s = b2[0];
    const float* row = g1 + (size_t)r * 128;
#pragma unroll
    for (int k = 0; k < 128; k += 4) {
        float4 v = *(const float4*)&row[k];
        s += v.x * w[k] + v.y * w[k + 1] + v.z * w[k + 2] + v.w * w[k + 3];
    }
    out[r] = 1.f / (1.f + __expf(-s));
}

extern "C" void kernel_launch(void* const* d_in, const int* in_sizes, int n_in,
                              void* d_out, int out_size, void* d_ws, size_t ws_size,
                              hipStream_t stream) {
    const float* x        = (const float*)d_in[0];
    const int*   edge_row = (const int*)d_in[1];
    const int*   edge_col = (const int*)d_in[2];
    const float* edge_val = (const float*)d_in[3];
    const float* pe       = (const float*)d_in[4];
    const float* W_in     = (const float*)d_in[5];
    const float* b_in     = (const float*)d_in[6];
    const float* W_pe     = (const float*)d_in[7];
    const float* b_pe     = (const float*)d_in[8];
    const float* gcn_W    = (const float*)d_in[9];
    const float* attn_in_W  = (const float*)d_in[10];
    const float* attn_in_b  = (const float*)d_in[11];
    const float* attn_out_W = (const float*)d_in[12];
    const float* attn_out_b = (const float*)d_in[13];
    const float* bn_g     = (const float*)d_in[14];
    const float* bn_b     = (const float*)d_in[15];
    const float* ffn_W1   = (const float*)d_in[16];
    const float* ffn_b1   = (const float*)d_in[17];
    const float* ffn_W2   = (const float*)d_in[18];
    const float* ffn_b2   = (const float*)d_in[19];
    const float* head_W1  = (const float*)d_in[20];
    const float* head_b1  = (const float*)d_in[21];
    const float* head_W2  = (const float*)d_in[22];
    const float* head_b2  = (const float*)d_in[23];
    float* out = (float*)d_out;

    float* w = (float*)d_ws;
    float* h    = w; w += 2097152;       // (8192,256) fp32
    float* buf1 = w; w += 8388608;       // (8192,1024) fp32 — gcn t1 / qkv / head mid
    float* buf2 = w; w += 2097152;       // (8192,256) fp32 — gcn gather out / ffn2 out
    float* buf3 = w; w += 2097152;       // (8192,256) fp32 — attn-proj out
    float* psum = w; w += 65536;
    float* psq  = w; w += 65536;
    float* scale = w; w += 256;
    float* shift = w; w += 256;
    int* counts    = (int*)w; w += 8192;
    int* row_start = (int*)w; w += 8224;
    int* cursor    = (int*)w; w += 8192;
    int* csr_e     = (int*)w; w += 131072;
    // bf16 region (u16 counts)
    u16* hb   = (u16*)w;              // (8192,256)
    u16* xb   = hb + 2097152;         // (8192,128)
    u16* aob  = xb + 1048576;         // (8192,256) attn out bf16
    u16* wbWin = aob + 2097152;       // 32768
    u16* wbGcn = wbWin + 32768;       // 4*65536
    u16* wbAin = wbGcn + 262144;      // 4*196608
    u16* wbAout = wbAin + 786432;     // 4*65536
    u16* wbF1  = wbAout + 262144;     // 4*262144
    u16* wbF2  = wbF1 + 1048576;      // 4*262144
    u16* wbH1  = wbF2 + 1048576;      // 32768
    // ffn mid bf16 aliases buf1 (buf1's fp32 use finishes before ffn1 writes it)
    u16* midb = (u16*)buf1;

    // CSR build
    hipMemsetAsync(counts, 0, 8192 * sizeof(int), stream);
    hist_kernel<<<512, 256, 0, stream>>>(edge_row, counts);
    prefix_kernel<<<1, 256, 0, stream>>>(counts, row_start, cursor);
    scatter_kernel<<<512, 256, 0, stream>>>(edge_row, cursor, csr_e);

    // bf16 casts (per-launch, graph-safe). grids = n/1024 (4 elems/thread).
    cast_bf16_kernel<<<1024, 256, 0, stream>>>(x, xb);
    cast_bf16_kernel<<<32, 256, 0, stream>>>(W_in, wbWin);
    cast_bf16_kernel<<<256, 256, 0, stream>>>(gcn_W, wbGcn);
    cast_bf16_kernel<<<768, 256, 0, stream>>>(attn_in_W, wbAin);
    cast_bf16_kernel<<<256, 256, 0, stream>>>(attn_out_W, wbAout);
    cast_bf16_kernel<<<1024, 256, 0, stream>>>(ffn_W1, wbF1);
    cast_bf16_kernel<<<1024, 256, 0, stream>>>(ffn_W2, wbF2);
    cast_bf16_kernel<<<32, 256, 0, stream>>>(head_W1, wbH1);

    // input projection (MFMA) + PE add
    gemm_mfma<0, 0><<<dim3(4, 64), 256, 0, stream>>>(xb, wbWin, b_in, h, BN, D_IN, HH);
    pe_add_kernel<<<BN, 256, 0, stream>>>(pe, W_pe, b_pe, h, hb);

    for (int l = 0; l < LL; ++l) {
        // GCN: t1 = hb @ gcn_W^T (fp32 out), gather+gelu, BN
        gemm_mfma<0, 0><<<dim3(4, 64), 256, 0, stream>>>(hb, wbGcn + l * 65536, nullptr, buf1, BN, HH, HH);
        gcn_gather_kernel<<<2048, 256, 0, stream>>>(buf1, row_start, csr_e, edge_col, edge_val, buf2);
        bn_reduce_kernel<<<256, 256, 0, stream>>>(h, buf2, psum, psq);
        bn_finalize_kernel<<<1, 256, 0, stream>>>(psum, psq, bn_g + (l * 3 + 0) * 256, bn_b + (l * 3 + 0) * 256, scale, shift);
        bn_apply_kernel<<<2048, 256, 0, stream>>>(h, hb, scale, shift);

        // attention
        gemm_mfma<0, 0><<<dim3(12, 64), 256, 0, stream>>>(hb, wbAin + l * 196608, attn_in_b + l * 768, buf1, BN, HH, 768);
        attn_kernel<<<1024, 256, 0, stream>>>(buf1, aob);
        gemm_mfma<0, 0><<<dim3(4, 64), 256, 0, stream>>>(aob, wbAout + l * 65536, attn_out_b + l * 256, buf3, BN, HH, HH);
        bn_reduce_kernel<<<256, 256, 0, stream>>>(h, buf3, psum, psq);
        bn_finalize_kernel<<<1, 256, 0, stream>>>(psum, psq, bn_g + (l * 3 + 1) * 256, bn_b + (l * 3 + 1) * 256, scale, shift);
        bn_apply_kernel<<<2048, 256, 0, stream>>>(h, hb, scale, shift);

        // FFN: mid = gelu(hb @ W1^T) -> bf16 (aliases buf1); out = mid @ W2^T fp32
        gemm_mfma<1, 1><<<dim3(16, 64), 256, 0, stream>>>(hb, wbF1 + l * 262144, ffn_b1 + l * 1024, midb, BN, HH, 1024);
        gemm_mfma<0, 0><<<dim3(4, 64), 256, 0, stream>>>(midb, wbF2 + l * 262144, ffn_b2 + l * 256, buf2, BN, 1024, HH);
        bn_reduce_kernel<<<256, 256, 0, stream>>>(h, buf2, psum, psq);
        bn_finalize_kernel<<<1, 256, 0, stream>>>(psum, psq, bn_g + (l * 3 + 2) * 256, bn_b + (l * 3 + 2) * 256, scale, shift);
        bn_apply_kernel<<<2048, 256, 0, stream>>>(h, hb, scale, shift);
    }

    // head: g1 = gelu(hb @ head_W1^T) fp32 ; out = sigmoid(g1 @ head_W2^T + b2)
    gemm_mfma<1, 0><<<dim3(2, 64), 256, 0, stream>>>(hb, wbH1, head_b1, buf1, BN, HH, 128);
    head2_kernel<<<32, 256, 0, stream>>>(buf1, head_W2, head_b2, out);
}

// Round 5
// 962.676 us; speedup vs baseline: 3.0500x; 1.6342x over previous
//
#include <hip/hip_runtime.h>
#include <hip/hip_bf16.h>
#include <math.h>

// Problem constants
#define BB 8
#define NN 1024
#define BN 8192
#define D_IN 128
#define HH 256
#define LL 4
#define NHD 8
#define DH 32
#define EE 131072
#define EPSV 1e-5f

typedef unsigned short u16;
typedef unsigned int u32;
typedef __attribute__((ext_vector_type(8))) short bf16x8;
typedef __attribute__((ext_vector_type(4))) float f32x4;

__device__ __forceinline__ float gelu_erf(float x) {
    return 0.5f * x * (1.0f + erff(x * 0.70710678118654752f));
}

__device__ __forceinline__ u16 f2bf(float v) {
    __hip_bfloat16 b = __float2bfloat16(v);   // RNE
    return *reinterpret_cast<u16*>(&b);
}

__device__ __forceinline__ float bf2f(u16 u) {
    u32 x = ((u32)u) << 16;
    return __builtin_bit_cast(float, x);
}

__device__ __forceinline__ u32 pack2bf(float lo, float hi) {
    return ((u32)f2bf(hi) << 16) | (u32)f2bf(lo);
}

// ---------------- fp32 -> bf16 cast (4 elems/thread) ----------------
__global__ __launch_bounds__(256) void cast_bf16_kernel(const float* __restrict__ in,
                                                        u16* __restrict__ out) {
    int i = blockIdx.x * 256 + threadIdx.x;
    float4 v = ((const float4*)in)[i];
    ushort4 o;
    o.x = f2bf(v.x); o.y = f2bf(v.y); o.z = f2bf(v.z); o.w = f2bf(v.w);
    ((ushort4*)out)[i] = o;
}

// ---------------- CSR build ----------------
__global__ __launch_bounds__(256) void hist_kernel(const int* __restrict__ edge_row,
                                                   int* __restrict__ counts) {
    int e = blockIdx.x * 256 + threadIdx.x;
    atomicAdd(&counts[edge_row[e]], 1);
}

__global__ __launch_bounds__(256) void prefix_kernel(const int* __restrict__ counts,
                                                     int* __restrict__ row_start,
                                                     int* __restrict__ cursor) {
    __shared__ int lds[256];
    int t = threadIdx.x;
    int local[32];
    int s = 0;
#pragma unroll
    for (int i = 0; i < 32; ++i) { local[i] = counts[t * 32 + i]; s += local[i]; }
    lds[t] = s;
    __syncthreads();
    for (int off = 1; off < 256; off <<= 1) {
        int v = (t >= off) ? lds[t - off] : 0;
        __syncthreads();
        lds[t] += v;
        __syncthreads();
    }
    int excl = (t == 0) ? 0 : lds[t - 1];
#pragma unroll
    for (int i = 0; i < 32; ++i) {
        int c = local[i];
        row_start[t * 32 + i] = excl;
        cursor[t * 32 + i] = excl;
        excl += c;
    }
    if (t == 255) row_start[8192] = excl;
}

__global__ __launch_bounds__(256) void scatter_kernel(const int* __restrict__ edge_row,
                                                      int* __restrict__ cursor,
                                                      int* __restrict__ csr_e) {
    int e = blockIdx.x * 256 + threadIdx.x;
    int r = edge_row[e];
    int pos = atomicAdd(&cursor[r], 1);
    csr_e[pos] = e;
}

// ---------------- GCN gather: out[r] = gelu(sum_e val[e]*t1[col[e]]) ----------------
__global__ __launch_bounds__(256) void gcn_gather_kernel(const float* __restrict__ t1,
                                                         const int* __restrict__ row_start,
                                                         const int* __restrict__ csr_e,
                                                         const int* __restrict__ edge_col,
                                                         const float* __restrict__ edge_val,
                                                         float* __restrict__ outb) {
    int wave = threadIdx.x >> 6;
    int lane = threadIdx.x & 63;
    int r = blockIdx.x * 4 + wave;
    float4 acc = make_float4(0.f, 0.f, 0.f, 0.f);
    int p0 = row_start[r], p1 = row_start[r + 1];
    for (int p = p0; p < p1; ++p) {
        int e = csr_e[p];
        int c = edge_col[e];
        float v = edge_val[e];
        float4 src = *(const float4*)&t1[(size_t)c * HH + lane * 4];
        acc.x += v * src.x; acc.y += v * src.y; acc.z += v * src.z; acc.w += v * src.w;
    }
    float4 g;
    g.x = gelu_erf(acc.x); g.y = gelu_erf(acc.y); g.z = gelu_erf(acc.z); g.w = gelu_erf(acc.w);
    *(float4*)&outb[(size_t)r * HH + lane * 4] = g;
}

// ---------------- BatchNorm (3 phases) ----------------
__global__ __launch_bounds__(256) void bn_reduce_kernel(float* __restrict__ h,
                                                        const float* __restrict__ add,
                                                        float* __restrict__ psum,
                                                        float* __restrict__ psq) {
    int c = threadIdx.x;
    int chunk = blockIdx.x;
    int r0 = chunk * 32;
    float s = 0.f, q = 0.f;
#pragma unroll 4
    for (int i = 0; i < 32; ++i) {
        int idx = (r0 + i) * HH + c;
        float v = h[idx] + add[idx];
        h[idx] = v;
        s += v; q += v * v;
    }
    psum[chunk * HH + c] = s;
    psq[chunk * HH + c] = q;
}

__global__ __launch_bounds__(256) void bn_finalize_kernel(const float* __restrict__ psum,
                                                          const float* __restrict__ psq,
                                                          const float* __restrict__ g,
                                                          const float* __restrict__ b,
                                                          float* __restrict__ scale,
                                                          float* __restrict__ shift) {
    int c = threadIdx.x;
    float s = 0.f, q = 0.f;
    for (int i = 0; i < 256; ++i) { s += psum[i * HH + c]; q += psq[i * HH + c]; }
    float mean = s * (1.f / 8192.f);
    float var = q * (1.f / 8192.f) - mean * mean;
    float sc = g[c] * rsqrtf(var + EPSV);
    scale[c] = sc;
    shift[c] = b[c] - mean * sc;
}

// writes fp32 h and bf16 hb
__global__ __launch_bounds__(256) void bn_apply_kernel(float* __restrict__ h,
                                                       u16* __restrict__ hb,
                                                       const float* __restrict__ scale,
                                                       const float* __restrict__ shift) {
    int i = blockIdx.x * 256 + threadIdx.x;   // float4 index over BN*H/4
    float4 v = ((float4*)h)[i];
    int c4 = (i & 63) * 4;                    // 64 float4 per row of 256
    v.x = v.x * scale[c4 + 0] + shift[c4 + 0];
    v.y = v.y * scale[c4 + 1] + shift[c4 + 1];
    v.z = v.z * scale[c4 + 2] + shift[c4 + 2];
    v.w = v.w * scale[c4 + 3] + shift[c4 + 3];
    ((float4*)h)[i] = v;
    ushort4 o;
    o.x = f2bf(v.x); o.y = f2bf(v.y); o.z = f2bf(v.z); o.w = f2bf(v.w);
    ((ushort4*)hb)[i] = o;
}

// ---------------- bf16 MFMA GEMM: C[M,N] = A[M,K] @ W[N,K]^T + bias ----------------
#define SWZ(row, c8) ((c8) ^ (((row) & 7) << 3))
template <int EPI, int OUTBF>
__global__ __launch_bounds__(256) void gemm_mfma(const u16* __restrict__ A,
                                                 const u16* __restrict__ W,
                                                 const float* __restrict__ bias,
                                                 void* __restrict__ Cout,
                                                 int M, int K, int N) {
    __shared__ u16 As[128][64];
    __shared__ u16 Ws[64][64];
    int t = threadIdx.x;
    int bm = blockIdx.y * 128, bn = blockIdx.x * 64;
    int wid = t >> 6, lane = t & 63;
    int wr = wid >> 1, wc = wid & 1;
    int lr = lane & 15, lg = lane >> 4;

    f32x4 zero = {0.f, 0.f, 0.f, 0.f};
    f32x4 acc[4][2];
#pragma unroll
    for (int mi = 0; mi < 4; ++mi)
#pragma unroll
        for (int ni = 0; ni < 2; ++ni) acc[mi][ni] = zero;

    int sr = t >> 3;            // 0..31 staging row
    int c8 = (t & 7) * 8;       // 0..56 staging col (8 bf16 = 16B)

    for (int k0 = 0; k0 < K; k0 += 64) {
        __syncthreads();
#pragma unroll
        for (int p = 0; p < 4; ++p) {
            int row = sr + p * 32;
            const u16* src = A + (size_t)(bm + row) * K + k0 + c8;
            *(int4*)&As[row][SWZ(row, c8)] = *(const int4*)src;
        }
#pragma unroll
        for (int p = 0; p < 2; ++p) {
            int row = sr + p * 32;
            const u16* src = W + (size_t)(bn + row) * K + k0 + c8;
            *(int4*)&Ws[row][SWZ(row, c8)] = *(const int4*)src;
        }
        __syncthreads();
#pragma unroll
        for (int kk = 0; kk < 2; ++kk) {
            bf16x8 af[4], bf[2];
#pragma unroll
            for (int mi = 0; mi < 4; ++mi) {
                int row = wr * 64 + mi * 16 + lr;
                af[mi] = *(const bf16x8*)&As[row][SWZ(row, kk * 32 + lg * 8)];
            }
#pragma unroll
            for (int ni = 0; ni < 2; ++ni) {
                int row = wc * 32 + ni * 16 + lr;
                bf[ni] = *(const bf16x8*)&Ws[row][SWZ(row, kk * 32 + lg * 8)];
            }
#pragma unroll
            for (int mi = 0; mi < 4; ++mi)
#pragma unroll
                for (int ni = 0; ni < 2; ++ni)
                    acc[mi][ni] = __builtin_amdgcn_mfma_f32_16x16x32_bf16(af[mi], bf[ni], acc[mi][ni], 0, 0, 0);
        }
    }

#pragma unroll
    for (int ni = 0; ni < 2; ++ni) {
        int col = bn + wc * 32 + ni * 16 + lr;
        float bj = bias ? bias[col] : 0.f;
#pragma unroll
        for (int mi = 0; mi < 4; ++mi) {
#pragma unroll
            for (int r = 0; r < 4; ++r) {
                int row = bm + wr * 64 + mi * 16 + lg * 4 + r;
                float v = acc[mi][ni][r] + bj;
                if (EPI == 1) v = gelu_erf(v);
                if (OUTBF)
                    ((u16*)Cout)[(size_t)row * N + col] = f2bf(v);
                else
                    ((float*)Cout)[(size_t)row * N + col] = v;
            }
        }
    }
}

// small K=8 GEMM accumulate: h += pe @ W_pe^T + b_pe ; also emits bf16 hb
__global__ __launch_bounds__(256) void pe_add_kernel(const float* __restrict__ pe,
                                                     const float* __restrict__ Wpe,
                                                     const float* __restrict__ bpe,
                                                     float* __restrict__ h,
                                                     u16* __restrict__ hb) {
    __shared__ float Ws[256][9];
    int t = threadIdx.x;
    for (int i = t; i < 2048; i += 256) Ws[i >> 3][i & 7] = Wpe[i];
    __syncthreads();
    int r = blockIdx.x;   // one row per block
    int c = t;
    float s = bpe[c];
    const float* pr = pe + r * 8;
#pragma unroll
    for (int k = 0; k < 8; ++k) s += pr[k] * Ws[c][k];
    float nv = h[(size_t)r * HH + c] + s;
    h[(size_t)r * HH + c] = nv;
    hb[(size_t)r * HH + c] = f2bf(nv);
}

// ---------------- MFMA flash attention ----------------
// qkv: (BN,768) bf16 rows [q k v], per head 32 dims. o: (BN,256) bf16.
// grid = 8b*8h*16qt = 1024 blocks, 256 threads = 4 waves * 16 q-rows.
// Swapped QK^T: S^T = mfma(K_frag, Q_frag) -> lane holds 16 S for q=lane&15.
// PV as O^T = V^T @ P^T with V staged transposed; P^T -> B-frag via shuffles.
__global__ __launch_bounds__(256) void attn_mfma_kernel(const u16* __restrict__ qkv,
                                                        u16* __restrict__ o) {
    __shared__ __align__(16) u16 Ks[64][40];   // keys x d, pad 40 -> 8 bank-start spread
    __shared__ __align__(16) u16 Vt[32][72];   // d x keys, pad 72
    __shared__ __align__(16) u16 Ot[64][40];   // q-local x d (epilogue transpose)
    int bid = blockIdx.x;
    int qt = bid & 15;
    int head = (bid >> 4) & 7;
    int b = bid >> 7;
    int t = threadIdx.x;
    int w = t >> 6, lane = t & 63;
    int lr = lane & 15, lg = lane >> 4;

    // Q fragment (B-operand): row=q=lr, k-elems d = lg*8..+7 ; pre-scaled by 1/sqrt(DH)
    bf16x8 qf;
    {
        const u16* qsrc = qkv + (size_t)(b * NN + qt * 64 + w * 16 + lr) * 768 + head * DH + lg * 8;
        bf16x8 raw = *(const bf16x8*)qsrc;
#pragma unroll
        for (int j = 0; j < 8; ++j) {
            float f = bf2f((u16)raw[j]) * 0.17677669529663689f;
            qf[j] = (short)f2bf(f);
        }
    }

    f32x4 zero = {0.f, 0.f, 0.f, 0.f};
    f32x4 oacc[2] = {zero, zero};   // O^T frags: d = dh*16+lg*4+reg, q = lr
    float m = -1e30f, l = 0.f;

    int srow = t >> 2;              // staging: key row 0..63
    int sc8 = (t & 3) * 8;          // d chunk
    const u16* kvbase = qkv + (size_t)(b * NN) * 768 + 256 + head * DH + sc8;

    int srcA = ((lg & 1) << 5) + lr;   // P-shuffle source lanes
    int srcB = srcA + 16;
    int hi = lg >> 1;

    for (int k0 = 0; k0 < NN; k0 += 64) {
        __syncthreads();
        {
            const u16* src = kvbase + (size_t)(k0 + srow) * 768;
            *(int4*)&Ks[srow][sc8] = *(const int4*)src;          // K row-major
            bf16x8 vv = *(const bf16x8*)(src + 256);             // V -> transposed
#pragma unroll
            for (int j = 0; j < 8; ++j) Vt[sc8 + j][srow] = (u16)vv[j];
        }
        __syncthreads();

        // S^T frags: key = kt*16 + lg*4 + reg, q = lr (scale folded into qf)
        f32x4 st[4];
#pragma unroll
        for (int kt = 0; kt < 4; ++kt) {
            bf16x8 kf = *(const bf16x8*)&Ks[kt * 16 + lr][lg * 8];
            st[kt] = __builtin_amdgcn_mfma_f32_16x16x32_bf16(kf, qf, zero, 0, 0, 0);
        }

        // online softmax (per q = lr; data spread over lg groups)
        float tm = -1e30f;
#pragma unroll
        for (int kt = 0; kt < 4; ++kt)
#pragma unroll
            for (int r = 0; r < 4; ++r) tm = fmaxf(tm, st[kt][r]);
        tm = fmaxf(tm, __shfl_xor(tm, 16));
        tm = fmaxf(tm, __shfl_xor(tm, 32));
        float mn = fmaxf(m, tm);
        float corr = __expf(m - mn);
        l *= corr;
#pragma unroll
        for (int dh = 0; dh < 2; ++dh)
#pragma unroll
            for (int r = 0; r < 4; ++r) oacc[dh][r] *= corr;

        float ps = 0.f;
        u32 pw0[4], pw1[4];
#pragma unroll
        for (int kt = 0; kt < 4; ++kt) {
            float p0 = __expf(st[kt][0] - mn);
            float p1 = __expf(st[kt][1] - mn);
            float p2 = __expf(st[kt][2] - mn);
            float p3 = __expf(st[kt][3] - mn);
            ps += (p0 + p1) + (p2 + p3);
            pw0[kt] = pack2bf(p0, p1);
            pw1[kt] = pack2bf(p2, p3);
        }
        ps += __shfl_xor(ps, 16);
        ps += __shfl_xor(ps, 32);
        l += ps;
        m = mn;

        // PV: for key chunk c (32 keys): B-frag = P rows (q=lr, keys c*32+lg*8..+7)
#pragma unroll
        for (int c = 0; c < 2; ++c) {
            u32 w0a = (u32)__shfl((int)pw0[c * 2], srcA);
            u32 w0b = (u32)__shfl((int)pw0[c * 2 + 1], srcA);
            u32 w1a = (u32)__shfl((int)pw1[c * 2], srcA);
            u32 w1b = (u32)__shfl((int)pw1[c * 2 + 1], srcA);
            u32 w2a = (u32)__shfl((int)pw0[c * 2], srcB);
            u32 w2b = (u32)__shfl((int)pw0[c * 2 + 1], srcB);
            u32 w3a = (u32)__shfl((int)pw1[c * 2], srcB);
            u32 w3b = (u32)__shfl((int)pw1[c * 2 + 1], srcB);
            union { bf16x8 v; u32 u[4]; } pf;
            pf.u[0] = hi ? w0b : w0a;
            pf.u[1] = hi ? w1b : w1a;
            pf.u[2] = hi ? w2b : w2a;
            pf.u[3] = hi ? w3b : w3a;
#pragma unroll
            for (int dh = 0; dh < 2; ++dh) {
                bf16x8 vf = *(const bf16x8*)&Vt[dh * 16 + lr][c * 32 + lg * 8];
                oacc[dh] = __builtin_amdgcn_mfma_f32_16x16x32_bf16(vf, pf.v, oacc[dh], 0, 0, 0);
            }
        }
    }

    // epilogue: normalize, transpose through LDS, coalesced bf16 store
    float inv = 1.f / l;
    __syncthreads();
#pragma unroll
    for (int dh = 0; dh < 2; ++dh)
#pragma unroll
        for (int r = 0; r < 4; ++r)
            Ot[w * 16 + lr][dh * 16 + lg * 4 + r] = f2bf(oacc[dh][r] * inv);
    __syncthreads();
    {
        int orow = t >> 2, oc8 = (t & 3) * 8;
        u16* dst = o + (size_t)(b * NN + qt * 64 + orow) * HH + head * DH + oc8;
        *(int4*)dst = *(const int4*)&Ot[orow][oc8];
    }
}

// ---------------- head2: out = sigmoid(g1 @ W2^T + b2), N_out=1 ----------------
__global__ __launch_bounds__(256) void head2_kernel(const float* __restrict__ g1,
                                                    const float* __restrict__ W2,
                                                    const float* __restrict__ b2,
                                                    float* __restrict__ out) {
    __shared__ float w[128];
    int t = threadIdx.x;
    if (t < 128) w[t] = W2[t];
    __syncthreads();
    int r = blockIdx.x * 256 + t;
    float s = b2[0];
    const float* row = g1 + (size_t)r * 128;
#pragma unroll
    for (int k = 0; k < 128; k += 4) {
        float4 v = *(const float4*)&row[k];
        s += v.x * w[k] + v.y * w[k + 1] + v.z * w[k + 2] + v.w * w[k + 3];
    }
    out[r] = 1.f / (1.f + __expf(-s));
}

extern "C" void kernel_launch(void* const* d_in, const int* in_sizes, int n_in,
                              void* d_out, int out_size, void* d_ws, size_t ws_size,
                              hipStream_t stream) {
    const float* x        = (const float*)d_in[0];
    const int*   edge_row = (const int*)d_in[1];
    const int*   edge_col = (const int*)d_in[2];
    const float* edge_val = (const float*)d_in[3];
    const float* pe       = (const float*)d_in[4];
    const float* W_in     = (const float*)d_in[5];
    const float* b_in     = (const float*)d_in[6];
    const float* W_pe     = (const float*)d_in[7];
    const float* b_pe     = (const float*)d_in[8];
    const float* gcn_W    = (const float*)d_in[9];
    const float* attn_in_W  = (const float*)d_in[10];
    const float* attn_in_b  = (const float*)d_in[11];
    const float* attn_out_W = (const float*)d_in[12];
    const float* attn_out_b = (const float*)d_in[13];
    const float* bn_g     = (const float*)d_in[14];
    const float* bn_b     = (const float*)d_in[15];
    const float* ffn_W1   = (const float*)d_in[16];
    const float* ffn_b1   = (const float*)d_in[17];
    const float* ffn_W2   = (const float*)d_in[18];
    const float* ffn_b2   = (const float*)d_in[19];
    const float* head_W1  = (const float*)d_in[20];
    const float* head_b1  = (const float*)d_in[21];
    const float* head_W2  = (const float*)d_in[22];
    const float* head_b2  = (const float*)d_in[23];
    float* out = (float*)d_out;

    float* w = (float*)d_ws;
    float* h    = w; w += 2097152;       // (8192,256) fp32
    float* buf1 = w; w += 8388608;       // (8192,1024) fp32 — gcn t1 / head mid; u16 alias: qkv bf16 / ffn mid bf16
    float* buf2 = w; w += 2097152;       // (8192,256) fp32 — gcn gather out / ffn2 out
    float* buf3 = w; w += 2097152;       // (8192,256) fp32 — attn-proj out
    float* psum = w; w += 65536;
    float* psq  = w; w += 65536;
    float* scale = w; w += 256;
    float* shift = w; w += 256;
    int* counts    = (int*)w; w += 8192;
    int* row_start = (int*)w; w += 8224;
    int* cursor    = (int*)w; w += 8192;
    int* csr_e     = (int*)w; w += 131072;
    // bf16 region (u16 counts)
    u16* hb   = (u16*)w;              // (8192,256)
    u16* xb   = hb + 2097152;         // (8192,128)
    u16* aob  = xb + 1048576;         // (8192,256) attn out bf16
    u16* wbWin = aob + 2097152;       // 32768
    u16* wbGcn = wbWin + 32768;       // 4*65536
    u16* wbAin = wbGcn + 262144;      // 4*196608
    u16* wbAout = wbAin + 786432;     // 4*65536
    u16* wbF1  = wbAout + 262144;     // 4*262144
    u16* wbF2  = wbF1 + 1048576;      // 4*262144
    u16* wbH1  = wbF2 + 1048576;      // 32768
    // qkv bf16 and ffn-mid bf16 alias buf1 (time-disjoint uses)
    u16* qkvb = (u16*)buf1;
    u16* midb = (u16*)buf1;

    // CSR build
    hipMemsetAsync(counts, 0, 8192 * sizeof(int), stream);
    hist_kernel<<<512, 256, 0, stream>>>(edge_row, counts);
    prefix_kernel<<<1, 256, 0, stream>>>(counts, row_start, cursor);
    scatter_kernel<<<512, 256, 0, stream>>>(edge_row, cursor, csr_e);

    // bf16 casts (per-launch, graph-safe). grids = n/1024 (4 elems/thread).
    cast_bf16_kernel<<<1024, 256, 0, stream>>>(x, xb);
    cast_bf16_kernel<<<32, 256, 0, stream>>>(W_in, wbWin);
    cast_bf16_kernel<<<256, 256, 0, stream>>>(gcn_W, wbGcn);
    cast_bf16_kernel<<<768, 256, 0, stream>>>(attn_in_W, wbAin);
    cast_bf16_kernel<<<256, 256, 0, stream>>>(attn_out_W, wbAout);
    cast_bf16_kernel<<<1024, 256, 0, stream>>>(ffn_W1, wbF1);
    cast_bf16_kernel<<<1024, 256, 0, stream>>>(ffn_W2, wbF2);
    cast_bf16_kernel<<<32, 256, 0, stream>>>(head_W1, wbH1);

    // input projection (MFMA) + PE add
    gemm_mfma<0, 0><<<dim3(4, 64), 256, 0, stream>>>(xb, wbWin, b_in, h, BN, D_IN, HH);
    pe_add_kernel<<<BN, 256, 0, stream>>>(pe, W_pe, b_pe, h, hb);

    for (int l = 0; l < LL; ++l) {
        // GCN: t1 = hb @ gcn_W^T (fp32 out), gather+gelu, BN
        gemm_mfma<0, 0><<<dim3(4, 64), 256, 0, stream>>>(hb, wbGcn + l * 65536, nullptr, buf1, BN, HH, HH);
        gcn_gather_kernel<<<2048, 256, 0, stream>>>(buf1, row_start, csr_e, edge_col, edge_val, buf2);
        bn_reduce_kernel<<<256, 256, 0, stream>>>(h, buf2, psum, psq);
        bn_finalize_kernel<<<1, 256, 0, stream>>>(psum, psq, bn_g + (l * 3 + 0) * 256, bn_b + (l * 3 + 0) * 256, scale, shift);
        bn_apply_kernel<<<2048, 256, 0, stream>>>(h, hb, scale, shift);

        // attention: qkv bf16 -> MFMA flash attention -> out-proj
        gemm_mfma<0, 1><<<dim3(12, 64), 256, 0, stream>>>(hb, wbAin + l * 196608, attn_in_b + l * 768, qkvb, BN, HH, 768);
        attn_mfma_kernel<<<1024, 256, 0, stream>>>(qkvb, aob);
        gemm_mfma<0, 0><<<dim3(4, 64), 256, 0, stream>>>(aob, wbAout + l * 65536, attn_out_b + l * 256, buf3, BN, HH, HH);
        bn_reduce_kernel<<<256, 256, 0, stream>>>(h, buf3, psum, psq);
        bn_finalize_kernel<<<1, 256, 0, stream>>>(psum, psq, bn_g + (l * 3 + 1) * 256, bn_b + (l * 3 + 1) * 256, scale, shift);
        bn_apply_kernel<<<2048, 256, 0, stream>>>(h, hb, scale, shift);

        // FFN: mid = gelu(hb @ W1^T) -> bf16 (aliases buf1); out = mid @ W2^T fp32
        gemm_mfma<1, 1><<<dim3(16, 64), 256, 0, stream>>>(hb, wbF1 + l * 262144, ffn_b1 + l * 1024, midb, BN, HH, 1024);
        gemm_mfma<0, 0><<<dim3(4, 64), 256, 0, stream>>>(midb, wbF2 + l * 262144, ffn_b2 + l * 256, buf2, BN, 1024, HH);
        bn_reduce_kernel<<<256, 256, 0, stream>>>(h, buf2, psum, psq);
        bn_finalize_kernel<<<1, 256, 0, stream>>>(psum, psq, bn_g + (l * 3 + 2) * 256, bn_b + (l * 3 + 2) * 256, scale, shift);
        bn_apply_kernel<<<2048, 256, 0, stream>>>(h, hb, scale, shift);
    }

    // head: g1 = gelu(hb @ head_W1^T) fp32 ; out = sigmoid(g1 @ head_W2^T + b2)
    gemm_mfma<1, 0><<<dim3(2, 64), 256, 0, stream>>>(hb, wbH1, head_b1, buf1, BN, HH, 128);
    head2_kernel<<<32, 256, 0, stream>>>(buf1, head_W2, head_b2, out);
}

// Round 6
// 844.333 us; speedup vs baseline: 3.4775x; 1.1402x over previous
//
#include <hip/hip_runtime.h>
#include <hip/hip_bf16.h>
#include <math.h>

// Problem constants
#define BB 8
#define NN 1024
#define BN 8192
#define D_IN 128
#define HH 256
#define LL 4
#define NHD 8
#define DH 32
#define EE 131072
#define EPSV 1e-5f

typedef unsigned short u16;
typedef unsigned int u32;
typedef __attribute__((ext_vector_type(8))) short bf16x8;
typedef __attribute__((ext_vector_type(4))) float f32x4;

__device__ __forceinline__ float gelu_erf(float x) {
    return 0.5f * x * (1.0f + erff(x * 0.70710678118654752f));
}

__device__ __forceinline__ u16 f2bf(float v) {
    __hip_bfloat16 b = __float2bfloat16(v);   // RNE
    return *reinterpret_cast<u16*>(&b);
}

__device__ __forceinline__ float bf2f(u16 u) {
    u32 x = ((u32)u) << 16;
    return __builtin_bit_cast(float, x);
}

__device__ __forceinline__ u32 pack2bf(float lo, float hi) {
    return ((u32)f2bf(hi) << 16) | (u32)f2bf(lo);
}

// ---------------- all fp32->bf16 casts in ONE kernel (segments hardcoded) ----
__global__ __launch_bounds__(256) void cast_all_kernel(
        const float* s0, const float* s1, const float* s2, const float* s3,
        const float* s4, const float* s5, const float* s6, const float* s7,
        u16* d0, u16* d1, u16* d2, u16* d3, u16* d4, u16* d5, u16* d6, u16* d7) {
    int blk = blockIdx.x;
    const float* s; u16* d; int base;
    if      (blk < 1024) { s = s0; d = d0; base = 0; }
    else if (blk < 1056) { s = s1; d = d1; base = 1024; }
    else if (blk < 1312) { s = s2; d = d2; base = 1056; }
    else if (blk < 2080) { s = s3; d = d3; base = 1312; }
    else if (blk < 2336) { s = s4; d = d4; base = 2080; }
    else if (blk < 3360) { s = s5; d = d5; base = 2336; }
    else if (blk < 4384) { s = s6; d = d6; base = 3360; }
    else                 { s = s7; d = d7; base = 4384; }
    int i = (blk - base) * 256 + threadIdx.x;
    float4 v = ((const float4*)s)[i];
    ushort4 o;
    o.x = f2bf(v.x); o.y = f2bf(v.y); o.z = f2bf(v.z); o.w = f2bf(v.w);
    ((ushort4*)d)[i] = o;
}

// ---------------- CSR build ----------------
__global__ __launch_bounds__(256) void hist_kernel(const int* __restrict__ edge_row,
                                                   int* __restrict__ counts) {
    int e = blockIdx.x * 256 + threadIdx.x;
    atomicAdd(&counts[edge_row[e]], 1);
}

__global__ __launch_bounds__(256) void prefix_kernel(const int* __restrict__ counts,
                                                     int* __restrict__ row_start,
                                                     int* __restrict__ cursor) {
    __shared__ int lds[256];
    int t = threadIdx.x;
    int local[32];
    int s = 0;
#pragma unroll
    for (int i = 0; i < 32; ++i) { local[i] = counts[t * 32 + i]; s += local[i]; }
    lds[t] = s;
    __syncthreads();
    for (int off = 1; off < 256; off <<= 1) {
        int v = (t >= off) ? lds[t - off] : 0;
        __syncthreads();
        lds[t] += v;
        __syncthreads();
    }
    int excl = (t == 0) ? 0 : lds[t - 1];
#pragma unroll
    for (int i = 0; i < 32; ++i) {
        int c = local[i];
        row_start[t * 32 + i] = excl;
        cursor[t * 32 + i] = excl;
        excl += c;
    }
    if (t == 255) row_start[8192] = excl;
}

__global__ __launch_bounds__(256) void scatter_kernel(const int* __restrict__ edge_row,
                                                      int* __restrict__ cursor,
                                                      int* __restrict__ csr_e) {
    int e = blockIdx.x * 256 + threadIdx.x;
    int r = edge_row[e];
    int pos = atomicAdd(&cursor[r], 1);
    csr_e[pos] = e;
}

// ---------------- GCN gather (bf16 t1): out[r] = gelu(sum_e val[e]*t1[col[e]]) ----
__global__ __launch_bounds__(256) void gcn_gather_kernel(const u16* __restrict__ t1b,
                                                         const int* __restrict__ row_start,
                                                         const int* __restrict__ csr_e,
                                                         const int* __restrict__ edge_col,
                                                         const float* __restrict__ edge_val,
                                                         float* __restrict__ outb) {
    int wave = threadIdx.x >> 6;
    int lane = threadIdx.x & 63;
    int r = blockIdx.x * 4 + wave;
    float a0 = 0.f, a1 = 0.f, a2 = 0.f, a3 = 0.f;
    int p0 = row_start[r], p1 = row_start[r + 1];
    for (int p = p0; p < p1; ++p) {
        int e = csr_e[p];
        int c = edge_col[e];
        float v = edge_val[e];
        ushort4 sv = *(const ushort4*)&t1b[(size_t)c * HH + lane * 4];
        a0 += v * bf2f(sv.x); a1 += v * bf2f(sv.y);
        a2 += v * bf2f(sv.z); a3 += v * bf2f(sv.w);
    }
    float4 g;
    g.x = gelu_erf(a0); g.y = gelu_erf(a1); g.z = gelu_erf(a2); g.w = gelu_erf(a3);
    *(float4*)&outb[(size_t)r * HH + lane * 4] = g;
}

// ---------------- BatchNorm (3 phases) ----------------
__global__ __launch_bounds__(256) void bn_reduce_kernel(float* __restrict__ h,
                                                        const float* __restrict__ add,
                                                        float* __restrict__ psum,
                                                        float* __restrict__ psq) {
    int c = threadIdx.x;
    int chunk = blockIdx.x;
    int r0 = chunk * 32;
    float s = 0.f, q = 0.f;
#pragma unroll 4
    for (int i = 0; i < 32; ++i) {
        int idx = (r0 + i) * HH + c;
        float v = h[idx] + add[idx];
        h[idx] = v;
        s += v; q += v * v;
    }
    psum[chunk * HH + c] = s;
    psq[chunk * HH + c] = q;
}

// parallel finalize: 16 blocks x 16 channels, 16-group tree per channel
__global__ __launch_bounds__(256) void bn_finalize_kernel(const float* __restrict__ psum,
                                                          const float* __restrict__ psq,
                                                          const float* __restrict__ g,
                                                          const float* __restrict__ b,
                                                          float* __restrict__ scale,
                                                          float* __restrict__ shift) {
    __shared__ float ls[16][17], lq[16][17];
    int t = threadIdx.x;
    int cl = t & 15, grp = t >> 4;
    int c = blockIdx.x * 16 + cl;
    float s = 0.f, q = 0.f;
#pragma unroll
    for (int i = 0; i < 16; ++i) {
        int chunk = grp * 16 + i;
        s += psum[chunk * HH + c];
        q += psq[chunk * HH + c];
    }
    ls[grp][cl] = s; lq[grp][cl] = q;
    __syncthreads();
    if (t < 16) {
        float ss = 0.f, qq = 0.f;
#pragma unroll
        for (int gg = 0; gg < 16; ++gg) { ss += ls[gg][t]; qq += lq[gg][t]; }
        int ch = blockIdx.x * 16 + t;
        float mean = ss * (1.f / 8192.f);
        float var = qq * (1.f / 8192.f) - mean * mean;
        float sc = g[ch] * rsqrtf(var + EPSV);
        scale[ch] = sc;
        shift[ch] = b[ch] - mean * sc;
    }
}

// writes fp32 h and bf16 hb
__global__ __launch_bounds__(256) void bn_apply_kernel(float* __restrict__ h,
                                                       u16* __restrict__ hb,
                                                       const float* __restrict__ scale,
                                                       const float* __restrict__ shift) {
    int i = blockIdx.x * 256 + threadIdx.x;
    float4 v = ((float4*)h)[i];
    int c4 = (i & 63) * 4;
    v.x = v.x * scale[c4 + 0] + shift[c4 + 0];
    v.y = v.y * scale[c4 + 1] + shift[c4 + 1];
    v.z = v.z * scale[c4 + 2] + shift[c4 + 2];
    v.w = v.w * scale[c4 + 3] + shift[c4 + 3];
    ((float4*)h)[i] = v;
    ushort4 o;
    o.x = f2bf(v.x); o.y = f2bf(v.y); o.z = f2bf(v.z); o.w = f2bf(v.w);
    ((ushort4*)hb)[i] = o;
}

// ---------------- bf16 MFMA GEMM 128x64 tile ----------------
#define SWZ(row, c8) ((c8) ^ (((row) & 7) << 3))
template <int EPI, int OUTBF>
__global__ __launch_bounds__(256) void gemm_mfma(const u16* __restrict__ A,
                                                 const u16* __restrict__ W,
                                                 const float* __restrict__ bias,
                                                 void* __restrict__ Cout,
                                                 int M, int K, int N) {
    __shared__ u16 As[128][64];
    __shared__ u16 Ws[64][64];
    int t = threadIdx.x;
    int bm = blockIdx.y * 128, bn = blockIdx.x * 64;
    int wid = t >> 6, lane = t & 63;
    int wr = wid >> 1, wc = wid & 1;
    int lr = lane & 15, lg = lane >> 4;

    f32x4 zero = {0.f, 0.f, 0.f, 0.f};
    f32x4 acc[4][2];
#pragma unroll
    for (int mi = 0; mi < 4; ++mi)
#pragma unroll
        for (int ni = 0; ni < 2; ++ni) acc[mi][ni] = zero;

    int sr = t >> 3;
    int c8 = (t & 7) * 8;

    for (int k0 = 0; k0 < K; k0 += 64) {
        __syncthreads();
#pragma unroll
        for (int p = 0; p < 4; ++p) {
            int row = sr + p * 32;
            const u16* src = A + (size_t)(bm + row) * K + k0 + c8;
            *(int4*)&As[row][SWZ(row, c8)] = *(const int4*)src;
        }
#pragma unroll
        for (int p = 0; p < 2; ++p) {
            int row = sr + p * 32;
            const u16* src = W + (size_t)(bn + row) * K + k0 + c8;
            *(int4*)&Ws[row][SWZ(row, c8)] = *(const int4*)src;
        }
        __syncthreads();
#pragma unroll
        for (int kk = 0; kk < 2; ++kk) {
            bf16x8 af[4], bf[2];
#pragma unroll
            for (int mi = 0; mi < 4; ++mi) {
                int row = wr * 64 + mi * 16 + lr;
                af[mi] = *(const bf16x8*)&As[row][SWZ(row, kk * 32 + lg * 8)];
            }
#pragma unroll
            for (int ni = 0; ni < 2; ++ni) {
                int row = wc * 32 + ni * 16 + lr;
                bf[ni] = *(const bf16x8*)&Ws[row][SWZ(row, kk * 32 + lg * 8)];
            }
#pragma unroll
            for (int mi = 0; mi < 4; ++mi)
#pragma unroll
                for (int ni = 0; ni < 2; ++ni)
                    acc[mi][ni] = __builtin_amdgcn_mfma_f32_16x16x32_bf16(af[mi], bf[ni], acc[mi][ni], 0, 0, 0);
        }
    }

#pragma unroll
    for (int ni = 0; ni < 2; ++ni) {
        int col = bn + wc * 32 + ni * 16 + lr;
        float bj = bias ? bias[col] : 0.f;
#pragma unroll
        for (int mi = 0; mi < 4; ++mi) {
#pragma unroll
            for (int r = 0; r < 4; ++r) {
                int row = bm + wr * 64 + mi * 16 + lg * 4 + r;
                float v = acc[mi][ni][r] + bj;
                if (EPI == 1) v = gelu_erf(v);
                if (OUTBF)
                    ((u16*)Cout)[(size_t)row * N + col] = f2bf(v);
                else
                    ((float*)Cout)[(size_t)row * N + col] = v;
            }
        }
    }
}

// ---------------- bf16 MFMA GEMM 128x128 tile (N multiple of 128) ----------------
template <int EPI, int OUTBF>
__global__ __launch_bounds__(256) void gemm_mfma2(const u16* __restrict__ A,
                                                  const u16* __restrict__ W,
                                                  const float* __restrict__ bias,
                                                  void* __restrict__ Cout,
                                                  int M, int K, int N) {
    __shared__ u16 As[128][64];
    __shared__ u16 Ws[128][64];
    int t = threadIdx.x;
    int bm = blockIdx.y * 128, bn = blockIdx.x * 128;
    int wid = t >> 6, lane = t & 63;
    int wr = wid >> 1, wc = wid & 1;
    int lr = lane & 15, lg = lane >> 4;

    f32x4 zero = {0.f, 0.f, 0.f, 0.f};
    f32x4 acc[4][4];
#pragma unroll
    for (int mi = 0; mi < 4; ++mi)
#pragma unroll
        for (int ni = 0; ni < 4; ++ni) acc[mi][ni] = zero;

    int sr = t >> 3;
    int c8 = (t & 7) * 8;

    for (int k0 = 0; k0 < K; k0 += 64) {
        __syncthreads();
#pragma unroll
        for (int p = 0; p < 4; ++p) {
            int row = sr + p * 32;
            const u16* srcA = A + (size_t)(bm + row) * K + k0 + c8;
            *(int4*)&As[row][SWZ(row, c8)] = *(const int4*)srcA;
            const u16* srcW = W + (size_t)(bn + row) * K + k0 + c8;
            *(int4*)&Ws[row][SWZ(row, c8)] = *(const int4*)srcW;
        }
        __syncthreads();
#pragma unroll
        for (int kk = 0; kk < 2; ++kk) {
            bf16x8 af[4], bf[4];
#pragma unroll
            for (int mi = 0; mi < 4; ++mi) {
                int row = wr * 64 + mi * 16 + lr;
                af[mi] = *(const bf16x8*)&As[row][SWZ(row, kk * 32 + lg * 8)];
            }
#pragma unroll
            for (int ni = 0; ni < 4; ++ni) {
                int row = wc * 64 + ni * 16 + lr;
                bf[ni] = *(const bf16x8*)&Ws[row][SWZ(row, kk * 32 + lg * 8)];
            }
#pragma unroll
            for (int mi = 0; mi < 4; ++mi)
#pragma unroll
                for (int ni = 0; ni < 4; ++ni)
                    acc[mi][ni] = __builtin_amdgcn_mfma_f32_16x16x32_bf16(af[mi], bf[ni], acc[mi][ni], 0, 0, 0);
        }
    }

#pragma unroll
    for (int ni = 0; ni < 4; ++ni) {
        int col = bn + wc * 64 + ni * 16 + lr;
        float bj = bias ? bias[col] : 0.f;
#pragma unroll
        for (int mi = 0; mi < 4; ++mi) {
#pragma unroll
            for (int r = 0; r < 4; ++r) {
                int row = bm + wr * 64 + mi * 16 + lg * 4 + r;
                float v = acc[mi][ni][r] + bj;
                if (EPI == 1) v = gelu_erf(v);
                if (OUTBF)
                    ((u16*)Cout)[(size_t)row * N + col] = f2bf(v);
                else
                    ((float*)Cout)[(size_t)row * N + col] = v;
            }
        }
    }
}

// small K=8 GEMM accumulate: h += pe @ W_pe^T + b_pe ; also emits bf16 hb
__global__ __launch_bounds__(256) void pe_add_kernel(const float* __restrict__ pe,
                                                     const float* __restrict__ Wpe,
                                                     const float* __restrict__ bpe,
                                                     float* __restrict__ h,
                                                     u16* __restrict__ hb) {
    __shared__ float Ws[256][9];
    int t = threadIdx.x;
    for (int i = t; i < 2048; i += 256) Ws[i >> 3][i & 7] = Wpe[i];
    __syncthreads();
    int r = blockIdx.x;
    int c = t;
    float s = bpe[c];
    const float* pr = pe + r * 8;
#pragma unroll
    for (int k = 0; k < 8; ++k) s += pr[k] * Ws[c][k];
    float nv = h[(size_t)r * HH + c] + s;
    h[(size_t)r * HH + c] = nv;
    hb[(size_t)r * HH + c] = f2bf(nv);
}

// ---------------- V transpose: qkv V-part -> vT[b][h][d][key] ----------------
// 3-term XOR block swizzle keeps both LDS sides conflict-free (see analysis).
__global__ __launch_bounds__(256) void vtrans_kernel(const u16* __restrict__ qkv,
                                                     u16* __restrict__ vT) {
    __shared__ u16 Ls[64][64];
    int bid = blockIdx.x;
    int kt = bid & 15;
    int head = (bid >> 4) & 7;
    int b = bid >> 7;
    int t = threadIdx.x;
    // store phase: thread loads V[key_l][blkS*8..+7]
    int key_l = t >> 2, blkS = t & 3;
    const u16* src = qkv + (size_t)(b * NN + kt * 64 + key_l) * 768 + 512 + head * DH + blkS * 8;
    int sb = (blkS ^ (key_l & 7) ^ ((key_l >> 3) & 7)) * 8;
    *(int4*)&Ls[key_l][sb] = *(const int4*)src;
    __syncthreads();
    // read phase: thread gathers d = t>>3 across 8 consecutive keys kc*8..+7
    int d = t >> 3, kc = t & 7;
    union { u16 a[8]; int4 v; } tmp;
#pragma unroll
    for (int j = 0; j < 8; ++j) {
        int col = (((d >> 3) ^ j ^ kc) << 3) | (d & 7);
        tmp.a[j] = Ls[kc * 8 + j][col];
    }
    u16* dst = vT + (size_t)((b * 8 + head) * 32 + d) * NN + kt * 64 + kc * 8;
    *(int4*)dst = tmp.v;
}

// ---------------- MFMA flash attention (linear LDS staging, conflict-free) ----
__global__ __launch_bounds__(256) void attn_mfma_kernel(const u16* __restrict__ qkv,
                                                        const u16* __restrict__ vT,
                                                        u16* __restrict__ o) {
    __shared__ __align__(16) u16 Ks[64][40];   // keys x d
    __shared__ __align__(16) u16 Vt[32][72];   // d x keys (filled linearly from vT)
    __shared__ __align__(16) u16 Ot[64][40];
    int bid = blockIdx.x;
    int qt = bid & 15;
    int head = (bid >> 4) & 7;
    int b = bid >> 7;
    int t = threadIdx.x;
    int w = t >> 6, lane = t & 63;
    int lr = lane & 15, lg = lane >> 4;

    bf16x8 qf;
    {
        const u16* qsrc = qkv + (size_t)(b * NN + qt * 64 + w * 16 + lr) * 768 + head * DH + lg * 8;
        bf16x8 raw = *(const bf16x8*)qsrc;
#pragma unroll
        for (int j = 0; j < 8; ++j) {
            float f = bf2f((u16)raw[j]) * 0.17677669529663689f;
            qf[j] = (short)f2bf(f);
        }
    }

    f32x4 zero = {0.f, 0.f, 0.f, 0.f};
    f32x4 oacc[2] = {zero, zero};
    float m = -1e30f, l = 0.f;

    int srow = t >> 2, sc8 = (t & 3) * 8;      // K staging
    int vd = t >> 3, vc8 = (t & 7) * 8;        // V staging
    const u16* kbase = qkv + (size_t)(b * NN) * 768 + 256 + head * DH + sc8;
    const u16* vbase = vT + (size_t)((b * 8 + head) * 32 + vd) * NN + vc8;

    int srcA = ((lg & 1) << 5) + lr;
    int srcB = srcA + 16;
    int hi = lg >> 1;

    for (int k0 = 0; k0 < NN; k0 += 64) {
        __syncthreads();
        *(int4*)&Ks[srow][sc8] = *(const int4*)(kbase + (size_t)(k0 + srow) * 768);
        *(int4*)&Vt[vd][vc8] = *(const int4*)(vbase + k0);
        __syncthreads();

        f32x4 st[4];
#pragma unroll
        for (int kt = 0; kt < 4; ++kt) {
            bf16x8 kf = *(const bf16x8*)&Ks[kt * 16 + lr][lg * 8];
            st[kt] = __builtin_amdgcn_mfma_f32_16x16x32_bf16(kf, qf, zero, 0, 0, 0);
        }

        float tm = -1e30f;
#pragma unroll
        for (int kt = 0; kt < 4; ++kt)
#pragma unroll
            for (int r = 0; r < 4; ++r) tm = fmaxf(tm, st[kt][r]);
        tm = fmaxf(tm, __shfl_xor(tm, 16));
        tm = fmaxf(tm, __shfl_xor(tm, 32));
        float mn = fmaxf(m, tm);
        float corr = __expf(m - mn);
        l *= corr;
#pragma unroll
        for (int dh = 0; dh < 2; ++dh)
#pragma unroll
            for (int r = 0; r < 4; ++r) oacc[dh][r] *= corr;

        float ps = 0.f;
        u32 pw0[4], pw1[4];
#pragma unroll
        for (int kt = 0; kt < 4; ++kt) {
            float p0 = __expf(st[kt][0] - mn);
            float p1 = __expf(st[kt][1] - mn);
            float p2 = __expf(st[kt][2] - mn);
            float p3 = __expf(st[kt][3] - mn);
            ps += (p0 + p1) + (p2 + p3);
            pw0[kt] = pack2bf(p0, p1);
            pw1[kt] = pack2bf(p2, p3);
        }
        ps += __shfl_xor(ps, 16);
        ps += __shfl_xor(ps, 32);
        l += ps;
        m = mn;

#pragma unroll
        for (int c = 0; c < 2; ++c) {
            u32 w0a = (u32)__shfl((int)pw0[c * 2], srcA);
            u32 w0b = (u32)__shfl((int)pw0[c * 2 + 1], srcA);
            u32 w1a = (u32)__shfl((int)pw1[c * 2], srcA);
            u32 w1b = (u32)__shfl((int)pw1[c * 2 + 1], srcA);
            u32 w2a = (u32)__shfl((int)pw0[c * 2], srcB);
            u32 w2b = (u32)__shfl((int)pw0[c * 2 + 1], srcB);
            u32 w3a = (u32)__shfl((int)pw1[c * 2], srcB);
            u32 w3b = (u32)__shfl((int)pw1[c * 2 + 1], srcB);
            union { bf16x8 v; u32 u[4]; } pf;
            pf.u[0] = hi ? w0b : w0a;
            pf.u[1] = hi ? w1b : w1a;
            pf.u[2] = hi ? w2b : w2a;
            pf.u[3] = hi ? w3b : w3a;
#pragma unroll
            for (int dh = 0; dh < 2; ++dh) {
                bf16x8 vf = *(const bf16x8*)&Vt[dh * 16 + lr][c * 32 + lg * 8];
                oacc[dh] = __builtin_amdgcn_mfma_f32_16x16x32_bf16(vf, pf.v, oacc[dh], 0, 0, 0);
            }
        }
    }

    float inv = 1.f / l;
    __syncthreads();
#pragma unroll
    for (int dh = 0; dh < 2; ++dh)
#pragma unroll
        for (int r = 0; r < 4; ++r)
            Ot[w * 16 + lr][dh * 16 + lg * 4 + r] = f2bf(oacc[dh][r] * inv);
    __syncthreads();
    {
        int orow = t >> 2, oc8 = (t & 3) * 8;
        u16* dst = o + (size_t)(b * NN + qt * 64 + orow) * HH + head * DH + oc8;
        *(int4*)dst = *(const int4*)&Ot[orow][oc8];
    }
}

// ---------------- head2 ----------------
__global__ __launch_bounds__(256) void head2_kernel(const float* __restrict__ g1,
                                                    const float* __restrict__ W2,
                                                    const float* __restrict__ b2,
                                                    float* __restrict__ out) {
    __shared__ float w[128];
    int t = threadIdx.x;
    if (t < 128) w[t] = W2[t];
    __syncthreads();
    int r = blockIdx.x * 256 + t;
    float s = b2[0];
    const float* row = g1 + (size_t)r * 128;
#pragma unroll
    for (int k = 0; k < 128; k += 4) {
        float4 v = *(const float4*)&row[k];
        s += v.x * w[k] + v.y * w[k + 1] + v.z * w[k + 2] + v.w * w[k + 3];
    }
    out[r] = 1.f / (1.f + __expf(-s));
}

extern "C" void kernel_launch(void* const* d_in, const int* in_sizes, int n_in,
                              void* d_out, int out_size, void* d_ws, size_t ws_size,
                              hipStream_t stream) {
    const float* x        = (const float*)d_in[0];
    const int*   edge_row = (const int*)d_in[1];
    const int*   edge_col = (const int*)d_in[2];
    const float* edge_val = (const float*)d_in[3];
    const float* pe       = (const float*)d_in[4];
    const float* W_in     = (const float*)d_in[5];
    const float* b_in     = (const float*)d_in[6];
    const float* W_pe     = (const float*)d_in[7];
    const float* b_pe     = (const float*)d_in[8];
    const float* gcn_W    = (const float*)d_in[9];
    const float* attn_in_W  = (const float*)d_in[10];
    const float* attn_in_b  = (const float*)d_in[11];
    const float* attn_out_W = (const float*)d_in[12];
    const float* attn_out_b = (const float*)d_in[13];
    const float* bn_g     = (const float*)d_in[14];
    const float* bn_b     = (const float*)d_in[15];
    const float* ffn_W1   = (const float*)d_in[16];
    const float* ffn_b1   = (const float*)d_in[17];
    const float* ffn_W2   = (const float*)d_in[18];
    const float* ffn_b2   = (const float*)d_in[19];
    const float* head_W1  = (const float*)d_in[20];
    const float* head_b1  = (const float*)d_in[21];
    const float* head_W2  = (const float*)d_in[22];
    const float* head_b2  = (const float*)d_in[23];
    float* out = (float*)d_out;

    float* w = (float*)d_ws;
    float* h    = w; w += 2097152;       // (8192,256) fp32
    float* buf1 = w; w += 8388608;       // 32MB multi-use
    float* buf2 = w; w += 2097152;
    float* buf3 = w; w += 2097152;
    float* psum = w; w += 65536;
    float* psq  = w; w += 65536;
    float* scale = w; w += 256;
    float* shift = w; w += 256;
    int* counts    = (int*)w; w += 8192;
    int* row_start = (int*)w; w += 8224;
    int* cursor    = (int*)w; w += 8192;
    int* csr_e     = (int*)w; w += 131072;
    // bf16 region
    u16* hb   = (u16*)w;
    u16* xb   = hb + 2097152;
    u16* aob  = xb + 1048576;
    u16* wbWin = aob + 2097152;
    u16* wbGcn = wbWin + 32768;
    u16* wbAin = wbGcn + 262144;
    u16* wbAout = wbAin + 786432;
    u16* wbF1  = wbAout + 262144;
    u16* wbF2  = wbF1 + 1048576;
    u16* wbH1  = wbF2 + 1048576;
    // aliases inside buf1 (time-disjoint):
    //   t1b   : u16 [0 .. 2.10M)       (gcn linear out, read by gather)
    //   qkvb  : u16 [0 .. 6.29M)       (qkv bf16, read by vtrans+attn)
    //   midb  : u16 [0 .. 8.39M)       (ffn mid bf16)
    //   vT    : u16 [12.58M .. 14.68M) (transposed V, read by attn; dead by ffn1)
    u16* t1b  = (u16*)buf1;
    u16* qkvb = (u16*)buf1;
    u16* midb = (u16*)buf1;
    u16* vT   = (u16*)buf1 + 12582912;

    // CSR build
    hipMemsetAsync(counts, 0, 8192 * sizeof(int), stream);
    hist_kernel<<<512, 256, 0, stream>>>(edge_row, counts);
    prefix_kernel<<<1, 256, 0, stream>>>(counts, row_start, cursor);
    scatter_kernel<<<512, 256, 0, stream>>>(edge_row, cursor, csr_e);

    // all casts in one launch (segment blocks hardcoded in kernel)
    cast_all_kernel<<<4416, 256, 0, stream>>>(
        x, W_in, gcn_W, attn_in_W, attn_out_W, ffn_W1, ffn_W2, head_W1,
        xb, wbWin, wbGcn, wbAin, wbAout, wbF1, wbF2, wbH1);

    // input projection + PE add
    gemm_mfma<0, 0><<<dim3(4, 64), 256, 0, stream>>>(xb, wbWin, b_in, h, BN, D_IN, HH);
    pe_add_kernel<<<BN, 256, 0, stream>>>(pe, W_pe, b_pe, h, hb);

    for (int l = 0; l < LL; ++l) {
        // GCN: t1 = hb @ gcn_W^T (bf16 out), gather+gelu, BN
        gemm_mfma<0, 1><<<dim3(4, 64), 256, 0, stream>>>(hb, wbGcn + l * 65536, nullptr, t1b, BN, HH, HH);
        gcn_gather_kernel<<<2048, 256, 0, stream>>>(t1b, row_start, csr_e, edge_col, edge_val, buf2);
        bn_reduce_kernel<<<256, 256, 0, stream>>>(h, buf2, psum, psq);
        bn_finalize_kernel<<<16, 256, 0, stream>>>(psum, psq, bn_g + (l * 3 + 0) * 256, bn_b + (l * 3 + 0) * 256, scale, shift);
        bn_apply_kernel<<<2048, 256, 0, stream>>>(h, hb, scale, shift);

        // attention: qkv bf16 (128x128 GEMM) -> V transpose -> MFMA flash attn -> out-proj
        gemm_mfma2<0, 1><<<dim3(6, 64), 256, 0, stream>>>(hb, wbAin + l * 196608, attn_in_b + l * 768, qkvb, BN, HH, 768);
        vtrans_kernel<<<1024, 256, 0, stream>>>(qkvb, vT);
        attn_mfma_kernel<<<1024, 256, 0, stream>>>(qkvb, vT, aob);
        gemm_mfma<0, 0><<<dim3(4, 64), 256, 0, stream>>>(aob, wbAout + l * 65536, attn_out_b + l * 256, buf3, BN, HH, HH);
        bn_reduce_kernel<<<256, 256, 0, stream>>>(h, buf3, psum, psq);
        bn_finalize_kernel<<<16, 256, 0, stream>>>(psum, psq, bn_g + (l * 3 + 1) * 256, bn_b + (l * 3 + 1) * 256, scale, shift);
        bn_apply_kernel<<<2048, 256, 0, stream>>>(h, hb, scale, shift);

        // FFN
        gemm_mfma2<1, 1><<<dim3(8, 64), 256, 0, stream>>>(hb, wbF1 + l * 262144, ffn_b1 + l * 1024, midb, BN, HH, 1024);
        gemm_mfma<0, 0><<<dim3(4, 64), 256, 0, stream>>>(midb, wbF2 + l * 262144, ffn_b2 + l * 256, buf2, BN, 1024, HH);
        bn_reduce_kernel<<<256, 256, 0, stream>>>(h, buf2, psum, psq);
        bn_finalize_kernel<<<16, 256, 0, stream>>>(psum, psq, bn_g + (l * 3 + 2) * 256, bn_b + (l * 3 + 2) * 256, scale, shift);
        bn_apply_kernel<<<2048, 256, 0, stream>>>(h, hb, scale, shift);
    }

    // head
    gemm_mfma<1, 0><<<dim3(2, 64), 256, 0, stream>>>(hb, wbH1, head_b1, buf1, BN, HH, 128);
    head2_kernel<<<32, 256, 0, stream>>>(buf1, head_W2, head_b2, out);
}